// Round 14
// baseline (889.434 us; speedup 1.0000x reference)
//
#include <hip/hip_runtime.h>
#include <cstdint>
#include <cstddef>

// ---------------- workspace layout (floats) ----------------
static const size_t OFF_E1    = 0;         // [4,16,256,256]
static const size_t OFF_E2    = 4194304;   // [4,32,128,128]
static const size_t OFF_E3A   = 6291456;   // [4,64,64,64]
static const size_t OFF_E3B   = 7340032;   // [4,64,64,64]
static const size_t OFF_BIG16 = 8388608;   // s1 | attn o_part [6][4][64][4096] (spans big8) | d2raw
static const size_t OFF_BIG8  = 12582912;  // s2 then d3
static const size_t OFF_B4    = 14680064;  // s3 then bn-out
static const size_t OFF_V     = 15728640;  // vT [4,4096,64]
static const size_t OFF_Q     = 16777216;  // qT [4,4096,8]
static const size_t OFF_K     = 16908288;  // kC [4,8,4096]
static const size_t OFF_POOL  = 17039360;  // pool then wsum[4][64][9]
static const size_t OFF_SF1   = 17055744;
static const size_t OFF_SF2   = 17056000;
static const size_t OFF_ROW   = 17056256;
static const size_t OFF_D2LF  = 17072640;  // attn l_part [6][4][4096] | then [4,16,256,256]
static const size_t OFF_PRE   = 21266944;  // [4,3,256,256]

// ============== conv3x3 s1 p1, LDS-staged, multi-co per thread ==============
template<int C1, int C2, int BCAST2, int CIN_W, int W, int H, int ROWS,
         int CI_CH, int COUT, int CO_T, int RELU, int MIX, int WSUM>
__global__ __launch_bounds__(256) void k_c3(
    const float* __restrict__ in1, const float* __restrict__ in2,
    const float* __restrict__ w, const float* __restrict__ bias,
    const float* __restrict__ wsum, float* __restrict__ out)
{
  constexpr int CIN = C1 + C2;
  constexpr int PW = W + 4;
  constexpr int LR = ROWS + 2;
  __shared__ float lds[CI_CH * LR * PW];

  int tid = threadIdx.x;
  int tx = tid % W, ty = tid / W;
  int b = blockIdx.y;
  int co0 = blockIdx.z * CO_T;
  int oh0 = blockIdx.x * ROWS;
  int oh = oh0 + ty;

  float acc[CO_T];
#pragma unroll
  for (int i = 0; i < CO_T; ++i) acc[i] = bias[co0 + i];

  if (WSUM) {
    bool rv0 = oh - 1 >= 0, rv2 = oh + 1 < H;
    bool cv0 = tx - 1 >= 0, cv2 = tx + 1 < W;
    bool rv[3] = {rv0, true, rv2};
    bool cv[3] = {cv0, true, cv2};
    const float* wsp = wsum + ((long)b * COUT + co0) * 9;
#pragma unroll
    for (int co = 0; co < CO_T; ++co)
#pragma unroll
      for (int ky = 0; ky < 3; ++ky)
#pragma unroll
        for (int kx = 0; kx < 3; ++kx)
          acc[co] += (rv[ky] && cv[kx]) ? wsp[co * 9 + ky * 3 + kx] : 0.f;
  }

  for (int c0 = 0; c0 < CIN; c0 += CI_CH) {
    constexpr int TOTAL = CI_CH * LR * PW;
    for (int i = tid; i < TOTAL; i += 256) {
      int ci_l = i / (LR * PW);
      int rem = i % (LR * PW);
      int r = rem / PW, c = rem % PW;
      int ih = oh0 - 1 + r, iw = c - 1;
      int ci = c0 + ci_l;
      float v = 0.f;
      if ((unsigned)ih < (unsigned)H && (unsigned)iw < (unsigned)W) {
        if (ci < C1) v = in1[((long)(b * C1 + ci) * H + ih) * W + iw];
        else if (BCAST2) v = in2[b * C2 + ci - C1];
        else v = in2[((long)(b * C2 + ci - C1) * H + ih) * W + iw];
      }
      lds[i] = v;
    }
    __syncthreads();
#pragma unroll
    for (int ci_l = 0; ci_l < CI_CH; ++ci_l) {
      int ci = c0 + ci_l;
      float x[3][3];
#pragma unroll
      for (int ky = 0; ky < 3; ++ky)
#pragma unroll
        for (int kx = 0; kx < 3; ++kx)
          x[ky][kx] = lds[ci_l * (LR * PW) + (ty + ky) * PW + tx + kx];
      const float* wb = w + (long)ci * 9;
#pragma unroll
      for (int co = 0; co < CO_T; ++co) {
        const float* wp = wb + (long)(co0 + co) * CIN_W * 9;
#pragma unroll
        for (int ky = 0; ky < 3; ++ky)
#pragma unroll
          for (int kx = 0; kx < 3; ++kx)
            acc[co] += wp[ky * 3 + kx] * x[ky][kx];
      }
    }
    __syncthreads();
  }

#pragma unroll
  for (int co = 0; co < CO_T; ++co) {
    float a = acc[co];
    if (RELU) a = fmaxf(a, 0.f);
    if (MIX) {
      float m = in1[((long)(b * C1 + co0 + co) * H + oh) * W + tx];
      a = 0.99f * m + 0.01f * a;
    }
    out[((long)(b * COUT + co0 + co) * H + oh) * W + tx] = a;
  }
}

// ====== conv4x4 s2 p1 + relu, dual-branch merged launch, dbuf pipeline ======
template<int CIN, int CI_CH, int COUT, int CO_T, int WIN, int HIN, int TW, int TH>
__global__ __launch_bounds__(256) void k_c4dual(
    const float* __restrict__ in1, const float* __restrict__ w1,
    const float* __restrict__ b1, float* __restrict__ out1,
    const float* __restrict__ in2, const float* __restrict__ w2,
    const float* __restrict__ b2, float* __restrict__ out2)
{
  constexpr int ZSPLIT = COUT / CO_T;
  constexpr int Wo = WIN / 2, Ho = HIN / 2;
  constexpr int PW = 2 * TW + 4;
  constexpr int LR = 2 * TH + 2;
  constexpr int TOTAL = CI_CH * LR * PW;
  constexpr int SITER = (TOTAL + 255) / 256;
  constexpr int WTOT = CIN * CO_T * 16;
  __shared__ float lin[2][TOTAL];
  __shared__ float w_s[WTOT];

  int tid = threadIdx.x;
  int tx = tid % TW, ty = tid / TW;
  int b = blockIdx.y;
  int z = blockIdx.z;
  const float* in; const float* w; const float* bias; float* out; int co0;
  if (z < ZSPLIT) { in = in1; w = w1; bias = b1; out = out1; co0 = z * CO_T; }
  else            { in = in2; w = w2; bias = b2; out = out2; co0 = (z - ZSPLIT) * CO_T; }
  int oh0 = blockIdx.x * TH;
  int oh = oh0 + ty;
  int R0 = 2 * oh0 - 1;

  for (int i = tid; i < WTOT; i += 256) {
    int t = i & 15, co = (i >> 4) % CO_T, ci = (i >> 4) / CO_T;
    w_s[i] = w[((long)(co0 + co) * CIN + ci) * 16 + t];
  }

  float acc[CO_T];
#pragma unroll
  for (int i = 0; i < CO_T; ++i) acc[i] = bias[co0 + i];

  float sreg[SITER];
#pragma unroll
  for (int it = 0; it < SITER; ++it) {
    int i = tid + it * 256;
    float v = 0.f;
    if (i < TOTAL) {
      int ci_l = i / (LR * PW);
      int rem = i % (LR * PW);
      int r = rem / PW, c = rem % PW;
      int ih = R0 + r, iw = c - 1;
      if ((unsigned)ih < (unsigned)HIN && (unsigned)iw < (unsigned)WIN)
        v = in[((long)(b * CIN + ci_l) * HIN + ih) * WIN + iw];
    }
    sreg[it] = v;
  }
#pragma unroll
  for (int it = 0; it < SITER; ++it) {
    int i = tid + it * 256;
    if (i < TOTAL) lin[0][i] = sreg[it];
  }

  int cur = 0;
  for (int c0 = 0; c0 < CIN; c0 += CI_CH) {
    bool has_next = (c0 + CI_CH < CIN);
    if (has_next) {
#pragma unroll
      for (int it = 0; it < SITER; ++it) {
        int i = tid + it * 256;
        float v = 0.f;
        if (i < TOTAL) {
          int ci_l = i / (LR * PW);
          int rem = i % (LR * PW);
          int r = rem / PW, c = rem % PW;
          int ih = R0 + r, iw = c - 1;
          if ((unsigned)ih < (unsigned)HIN && (unsigned)iw < (unsigned)WIN)
            v = in[((long)(b * CIN + c0 + CI_CH + ci_l) * HIN + ih) * WIN + iw];
        }
        sreg[it] = v;
      }
    }
    __syncthreads();
#pragma unroll
    for (int ci_l = 0; ci_l < CI_CH; ++ci_l) {
      int ci = c0 + ci_l;
      float x[4][4];
#pragma unroll
      for (int ky = 0; ky < 4; ++ky)
#pragma unroll
        for (int kx = 0; kx < 4; ++kx)
          x[ky][kx] = lin[cur][ci_l * (LR * PW) + (2 * ty + ky) * PW + 2 * tx + kx];
#pragma unroll
      for (int co = 0; co < CO_T; ++co) {
        const float* wp = &w_s[(ci * CO_T + co) * 16];
        float4 wa = *(const float4*)(wp);
        float4 wb = *(const float4*)(wp + 4);
        float4 wc = *(const float4*)(wp + 8);
        float4 wd = *(const float4*)(wp + 12);
        acc[co] += wa.x*x[0][0] + wa.y*x[0][1] + wa.z*x[0][2] + wa.w*x[0][3]
                 + wb.x*x[1][0] + wb.y*x[1][1] + wb.z*x[1][2] + wb.w*x[1][3]
                 + wc.x*x[2][0] + wc.y*x[2][1] + wc.z*x[2][2] + wc.w*x[2][3]
                 + wd.x*x[3][0] + wd.y*x[3][1] + wd.z*x[3][2] + wd.w*x[3][3];
      }
    }
    if (has_next) {
#pragma unroll
      for (int it = 0; it < SITER; ++it) {
        int i = tid + it * 256;
        if (i < TOTAL) lin[cur ^ 1][i] = sreg[it];
      }
    }
    cur ^= 1;
  }

#pragma unroll
  for (int co = 0; co < CO_T; ++co)
    out[((long)(b * COUT + co0 + co) * Ho + oh) * Wo + tx] = fmaxf(acc[co], 0.f);
}

// ============== convT 4x4 s2 p1 + relu, w_s in LDS, dbuf pipeline ===========
template<int C1, int C2, int COUT, int CO_T, int WIN, int HIN, int TPR, int CI_CH>
__global__ __launch_bounds__(256) void k_ct(
    const float* __restrict__ in1, const float* __restrict__ in2,
    const float* __restrict__ w, const float* __restrict__ bias,
    float* __restrict__ out)
{
  constexpr int CIN = C1 + C2;
  constexpr int Wo = 2 * WIN, Ho = 2 * HIN;
  constexpr int PW = WIN + 4;
  constexpr int LR = TPR + 2;
  constexpr int TOTAL = CI_CH * LR * PW;
  constexpr int SITER = (TOTAL + 255) / 256;
  constexpr int WTOT = CIN * CO_T * 16;
  __shared__ float lin[2][TOTAL];
  __shared__ float w_s[WTOT];

  int tid = threadIdx.x;
  int s = tid % WIN, dt = tid / WIN;
  int b = blockIdx.y;
  int co0 = blockIdx.z * CO_T;
  int t0 = blockIdx.x * TPR;
  int t = t0 + dt;

  for (int i = tid; i < WTOT; i += 256) {
    int tt = i & 15, co = (i >> 4) % CO_T, ci = (i >> 4) / CO_T;
    w_s[i] = w[((long)ci * COUT + co0 + co) * 16 + tt];
  }

  float aee[CO_T], aeo[CO_T], aoe[CO_T], aoo[CO_T];
#pragma unroll
  for (int i = 0; i < CO_T; ++i) {
    float bb = bias[co0 + i];
    aee[i] = bb; aeo[i] = bb; aoe[i] = bb; aoo[i] = bb;
  }

  float sreg[SITER];
#pragma unroll
  for (int it = 0; it < SITER; ++it) {
    int i = tid + it * 256;
    float v = 0.f;
    if (i < TOTAL) {
      int ci_l = i / (LR * PW);
      int rem = i % (LR * PW);
      int r = rem / PW, c = rem % PW;
      int ih = t0 - 1 + r, iw = c - 1;
      if ((unsigned)ih < (unsigned)HIN && (unsigned)iw < (unsigned)WIN) {
        v = (ci_l < C1) ? in1[((long)(b * C1 + ci_l) * HIN + ih) * WIN + iw]
                        : in2[((long)(b * C2 + ci_l - C1) * HIN + ih) * WIN + iw];
      }
    }
    sreg[it] = v;
  }
#pragma unroll
  for (int it = 0; it < SITER; ++it) {
    int i = tid + it * 256;
    if (i < TOTAL) lin[0][i] = sreg[it];
  }

  int cur = 0;
  for (int c0 = 0; c0 < CIN; c0 += CI_CH) {
    bool has_next = (c0 + CI_CH < CIN);
    if (has_next) {
#pragma unroll
      for (int it = 0; it < SITER; ++it) {
        int i = tid + it * 256;
        float v = 0.f;
        if (i < TOTAL) {
          int ci_l = i / (LR * PW);
          int rem = i % (LR * PW);
          int r = rem / PW, c = rem % PW;
          int ih = t0 - 1 + r, iw = c - 1;
          int ci = c0 + CI_CH + ci_l;
          if ((unsigned)ih < (unsigned)HIN && (unsigned)iw < (unsigned)WIN) {
            v = (ci < C1) ? in1[((long)(b * C1 + ci) * HIN + ih) * WIN + iw]
                          : in2[((long)(b * C2 + ci - C1) * HIN + ih) * WIN + iw];
          }
        }
        sreg[it] = v;
      }
    }
    __syncthreads();
#pragma unroll
    for (int ci_l = 0; ci_l < CI_CH; ++ci_l) {
      int ci = c0 + ci_l;
      float x[3][3];
#pragma unroll
      for (int r = 0; r < 3; ++r)
#pragma unroll
        for (int c = 0; c < 3; ++c)
          x[r][c] = lin[cur][ci_l * (LR * PW) + (dt + r) * PW + s + c];
#pragma unroll
      for (int co = 0; co < CO_T; ++co) {
        const float* wp = &w_s[(ci * CO_T + co) * 16];
        float4 wa = *(const float4*)(wp);
        float4 wb = *(const float4*)(wp + 4);
        float4 wc = *(const float4*)(wp + 8);
        float4 wd = *(const float4*)(wp + 12);
        aee[co] += wb.y * x[1][1] + wb.w * x[1][0] + wd.y * x[0][1] + wd.w * x[0][0];
        aeo[co] += wb.x * x[1][2] + wb.z * x[1][1] + wd.x * x[0][2] + wd.z * x[0][1];
        aoe[co] += wa.y * x[2][1] + wa.w * x[2][0] + wc.y * x[1][1] + wc.w * x[1][0];
        aoo[co] += wa.x * x[2][2] + wa.z * x[2][1] + wc.x * x[1][2] + wc.z * x[1][1];
      }
    }
    if (has_next) {
#pragma unroll
      for (int it = 0; it < SITER; ++it) {
        int i = tid + it * 256;
        if (i < TOTAL) lin[cur ^ 1][i] = sreg[it];
      }
    }
    cur ^= 1;
  }

#pragma unroll
  for (int co = 0; co < CO_T; ++co) {
    long base = ((long)(b * COUT + co0 + co) * Ho + 2 * t) * Wo + 2 * s;
    float2 r0; r0.x = fmaxf(aee[co], 0.f); r0.y = fmaxf(aeo[co], 0.f);
    float2 r1; r1.x = fmaxf(aoe[co], 0.f); r1.y = fmaxf(aoo[co], 0.f);
    *(float2*)(out + base) = r0;
    *(float2*)(out + base + Wo) = r1;
  }
}

// ============== wsum precompute for style-merge broadcast channels ==========
__global__ __launch_bounds__(256) void k_wsum(
    const float* __restrict__ w, const float* __restrict__ sf,
    float* __restrict__ wsum)
{
  int b = blockIdx.x;
  for (int i = threadIdx.x; i < 576; i += 256) {
    int co = i / 9, t = i % 9;
    float s = 0.f;
    for (int ci = 0; ci < 64; ++ci)
      s += w[((long)co * 128 + 64 + ci) * 9 + t] * sf[b * 64 + ci];
    wsum[((long)b * 64 + co) * 9 + t] = s;
  }
}

// ===== merged q/k/v projection: y<4 -> V quarter, y==4 -> Q+K ==============
__global__ __launch_bounds__(256) void k_qkvproj(
    const float* __restrict__ x,
    const float* __restrict__ wq, const float* __restrict__ bq,
    const float* __restrict__ wk, const float* __restrict__ bk,
    const float* __restrict__ wv, const float* __restrict__ bv,
    float* __restrict__ qT, float* __restrict__ kC,
    float* __restrict__ vT, int N)
{
  int idx = blockIdx.x * 256 + threadIdx.x;
  int n = idx % N, b = idx / N;
  const float* src = x + (long)b * 64 * N + n;
  if (blockIdx.y < 4) {
    int cq = blockIdx.y * 16;
    float va[16];
#pragma unroll
    for (int c = 0; c < 16; ++c) va[c] = bv[cq + c];
    for (int ci = 0; ci < 64; ++ci) {
      float xv = src[(long)ci * N];
#pragma unroll
      for (int c = 0; c < 16; ++c) va[c] += wv[(cq + c) * 64 + ci] * xv;
    }
    float* vo = vT + ((long)b * N + n) * 64 + cq;
#pragma unroll
    for (int c = 0; c < 16; c += 4) {
      float4 o; o.x = va[c]; o.y = va[c+1]; o.z = va[c+2]; o.w = va[c+3];
      *(float4*)(vo + c) = o;
    }
  } else {
    float qa[8], ka[8];
#pragma unroll
    for (int c = 0; c < 8; ++c) { qa[c] = bq[c]; ka[c] = bk[c]; }
    for (int ci = 0; ci < 64; ++ci) {
      float xv = src[(long)ci * N];
#pragma unroll
      for (int c = 0; c < 8; ++c) {
        qa[c] += wq[c * 64 + ci] * xv;
        ka[c] += wk[c * 64 + ci] * xv;
      }
    }
    float* qo = qT + ((long)b * N + n) * 8;
#pragma unroll
    for (int c = 0; c < 8; ++c) qo[c] = qa[c];
#pragma unroll
    for (int c = 0; c < 8; ++c) kC[((long)b * 8 + c) * N + n] = ka[c];
  }
}

// ====== flash attention v7: V read from global (L1/L2), no v_s =============
// grid (32 n0-tiles, B, 6 splits): splits 0-3 have 11 tiles, 4-5 have 10.
// LDS = k_s + p_s only (~36 KB). PV: P from p_s (broadcast), V from global.
__global__ __launch_bounds__(256) void k_fattn(
    const float* __restrict__ qT, const float* __restrict__ kC,
    const float* __restrict__ vT, float* __restrict__ o_part,
    float* __restrict__ l_part, int N)
{
  __shared__ float k_s[8][68];
  __shared__ float p_s[64 * 132];    // [m][q] stride 132; reused as o_sT[c][q]

  int tid = threadIdx.x;
  int n0 = blockIdx.x * 128;
  int b = blockIdx.y;
  int split = blockIdx.z;
  int qg = tid >> 3;   // 0..31
  int xg = tid & 7;    // 0..7

  int tstart = split * 10 + min(split, 4);
  int tcount = 10 + (split < 4 ? 1 : 0);

  float qv[4][8];
#pragma unroll
  for (int i = 0; i < 4; ++i) {
    const float4* qp = (const float4*)(qT + ((long)b * N + n0 + qg * 4 + i) * 8);
    float4 a = qp[0], c = qp[1];
    qv[i][0]=a.x; qv[i][1]=a.y; qv[i][2]=a.z; qv[i][3]=a.w;
    qv[i][4]=c.x; qv[i][5]=c.y; qv[i][6]=c.z; qv[i][7]=c.w;
  }

  float o[4][8];
#pragma unroll
  for (int i = 0; i < 4; ++i)
#pragma unroll
    for (int j = 0; j < 8; ++j) o[i][j] = 0.f;
  float l[4] = {0.f, 0.f, 0.f, 0.f};

  const float* kbase = kC + (long)b * 8 * N;
  const float* vbase = vT + (long)b * N * 64;

  for (int t = tstart; t < tstart + tcount; ++t) {
    int m0 = t * 64;
    // stage K tile [8][64]
    {
      int kk = tid >> 5, seg = tid & 31;
      float2 kv2 = *(const float2*)(kbase + (long)kk * N + m0 + seg * 2);
      *(float2*)&k_s[kk][seg * 2] = kv2;
    }
    __syncthreads();   // (A) k_s ready; all waves done with prev-tile p_s

    // QK^T: s[4q][8m] for m = xg*8..+7
    float s[4][8];
#pragma unroll
    for (int i = 0; i < 4; ++i)
#pragma unroll
      for (int j = 0; j < 8; ++j) s[i][j] = 0.f;
#pragma unroll
    for (int kk = 0; kk < 8; ++kk) {
      float4 ka = *(const float4*)&k_s[kk][xg * 8];
      float4 kb = *(const float4*)&k_s[kk][xg * 8 + 4];
#pragma unroll
      for (int i = 0; i < 4; ++i) {
        float q = qv[i][kk];
        s[i][0] += q * ka.x; s[i][1] += q * ka.y; s[i][2] += q * ka.z; s[i][3] += q * ka.w;
        s[i][4] += q * kb.x; s[i][5] += q * kb.y; s[i][6] += q * kb.z; s[i][7] += q * kb.w;
      }
    }
#pragma unroll
    for (int i = 0; i < 4; ++i) {
#pragma unroll
      for (int j = 0; j < 8; ++j) {
        s[i][j] = __expf(s[i][j]);
        l[i] += s[i][j];
      }
    }
#pragma unroll
    for (int j = 0; j < 8; ++j) {
      float4 w4; w4.x = s[0][j]; w4.y = s[1][j]; w4.z = s[2][j]; w4.w = s[3][j];
      *(float4*)&p_s[(xg * 8 + j) * 132 + qg * 4] = w4;
    }
    __syncthreads();   // (B) p_s ready

    // PV: P from LDS (wave-broadcast), V straight from global (L1/L2-resident)
    const float* vt = vbase + (long)m0 * 64 + xg * 8;
#pragma unroll 4
    for (int mm = 0; mm < 16; ++mm) {
#pragma unroll
      for (int j = 0; j < 4; ++j) {
        int m = mm * 4 + j;
        float4 pr = *(const float4*)&p_s[m * 132 + qg * 4];
        float4 va = *(const float4*)(vt + m * 64);
        float4 vb4 = *(const float4*)(vt + m * 64 + 4);
#pragma unroll
        for (int i = 0; i < 4; ++i) {
          float p = (i == 0) ? pr.x : (i == 1) ? pr.y : (i == 2) ? pr.z : pr.w;
          o[i][0] += p * va.x;  o[i][1] += p * va.y;
          o[i][2] += p * va.z;  o[i][3] += p * va.w;
          o[i][4] += p * vb4.x; o[i][5] += p * vb4.y;
          o[i][6] += p * vb4.z; o[i][7] += p * vb4.w;
        }
      }
    }
    // no 3rd barrier: next tile's barrier (A) orders p_s overwrites
  }

#pragma unroll
  for (int i = 0; i < 4; ++i) {
#pragma unroll
    for (int d = 1; d < 8; d <<= 1) l[i] += __shfl_xor(l[i], d);
  }

  __syncthreads();   // all waves done with final PV before p_s reuse
#pragma unroll
  for (int j = 0; j < 8; ++j) {
    float4 w4; w4.x = o[0][j]; w4.y = o[1][j]; w4.z = o[2][j]; w4.w = o[3][j];
    *(float4*)&p_s[(xg * 8 + j) * 132 + qg * 4] = w4;
  }
  __syncthreads();
  float* obase = o_part + (long)split * 1048576 + ((long)b * 64) * 4096 + n0;
  for (int idx = tid; idx < 2048; idx += 256) {
    int c = idx >> 5, q4 = (idx & 31) << 2;
    float4 v4 = *(const float4*)&p_s[c * 132 + q4];
    *(float4*)(obase + (long)c * 4096 + q4) = v4;
  }
  if (xg == 0) {
    float4 lw; lw.x = l[0]; lw.y = l[1]; lw.z = l[2]; lw.w = l[3];
    *(float4*)&l_part[((long)split * 4 + b) * 4096 + n0 + qg * 4] = lw;
  }
}

// ============== attention combine (6 partials): out = g*(Σo)/(Σl) + x =======
__global__ __launch_bounds__(256) void k_attnfin(
    const float* __restrict__ op, const float* __restrict__ lp,
    const float* __restrict__ xb, const float* __restrict__ gamma_p,
    float* __restrict__ outb)
{
  int idx = blockIdx.x * 256 + threadIdx.x;   // covers 4*64*4096 = 1048576
  int n = idx & 4095;
  int b = idx >> 18;
  float g = gamma_p[0];
  float o = op[idx] + op[idx + 1048576] + op[idx + 2097152]
          + op[idx + 3145728] + op[idx + 4194304] + op[idx + 5242880];
  const float* lb = lp + b * 4096 + n;
  float l = lb[0] + lb[16384] + lb[32768] + lb[49152] + lb[65536] + lb[81920];
  outb[idx] = g * o / l + xb[idx];
}

// ================= adaptive avg pool to 8x8 ================================
__global__ __launch_bounds__(256) void k_pool8(
    const float* __restrict__ in, float* __restrict__ out, int B, int C, int H, int W)
{
  int idx = blockIdx.x * 256 + threadIdx.x;
  int total = B * C * 64;
  if (idx >= total) return;
  int ow = idx & 7, oh = (idx >> 3) & 7;
  int c = (idx >> 6) % C, b = idx / (64 * C);
  int bh = H / 8, bw = W / 8;
  const float* src = in + ((long)(b * C + c)) * H * W;
  float s = 0.f;
  for (int y = 0; y < bh; ++y)
    for (int x = 0; x < bw; ++x)
      s += src[(oh * bh + y) * W + ow * bw + x];
  out[idx] = s / (float)(bh * bw);
}

// ================= fc + relu (wave per output) ==============================
__global__ __launch_bounds__(256) void k_fc_relu(
    const float* __restrict__ in, const float* __restrict__ w,
    const float* __restrict__ bias, float* __restrict__ out, int B, int K, int O)
{
  int gi = blockIdx.x * 4 + (threadIdx.x >> 6);
  int lane = threadIdx.x & 63;
  if (gi >= B * O) return;
  int b = gi / O, o = gi % O;
  const float* x = in + (long)b * K;
  const float* wp = w + (long)o * K;
  float s = 0.f;
  for (int i = lane; i < K; i += 64) s += x[i] * wp[i];
#pragma unroll
  for (int d = 1; d < 64; d <<= 1) s += __shfl_xor(s, d);
  if (lane == 0) out[gi] = fmaxf(s + bias[o], 0.f);
}

// ================= line filter: per-row std -> sigmoid mask =================
__global__ __launch_bounds__(256) void k_lf_rowstat(
    const float* __restrict__ x, float* __restrict__ mask_raw, int rows, int W)
{
  int row = blockIdx.x * 4 + (threadIdx.x >> 6);
  int lane = threadIdx.x & 63;
  if (row >= rows) return;
  const float* p = x + (long)row * W;
  float s = 0.f;
  for (int i = lane; i < W; i += 64) s += p[i];
#pragma unroll
  for (int d = 1; d < 64; d <<= 1) s += __shfl_xor(s, d);
  float mean = s / (float)W;
  float v = 0.f;
  for (int i = lane; i < W; i += 64) { float t = p[i] - mean; v += t * t; }
#pragma unroll
  for (int d = 1; d < 64; d <<= 1) v += __shfl_xor(v, d);
  float stdv = sqrtf(v / (float)(W - 1));
  float mask = 1.f / (1.f + __expf(-(0.05f - stdv) * 10.f));
  if (lane == 0) mask_raw[row] = mask;
}

// ================= line filter apply (+optional tanh) =======================
__global__ __launch_bounds__(256) void k_lf_apply(
    const float* __restrict__ x, const float* __restrict__ mask_raw,
    float* __restrict__ out, int BC, int H, int W, float strength, int do_tanh)
{
  long idx = (long)blockIdx.x * 256 + threadIdx.x;
  long total = (long)BC * H * W;
  if (idx >= total) return;
  int wcol = (int)(idx % W);
  int h = (int)((idx / W) % H);
  int bc = (int)(idx / ((long)W * H));
  const float* px = x + (long)bc * H * W;
  const float* pm = mask_raw + (long)bc * H;
  float vs = 0.f, mb = 0.f;
#pragma unroll
  for (int d = -2; d <= 2; ++d) {
    int hh = h + d; hh = hh < 0 ? 0 : (hh >= H ? H - 1 : hh);
    vs += px[hh * W + wcol];
    mb += pm[hh];
  }
  vs *= 0.2f; mb *= 0.2f;
  float m = mb * strength;
  float o = x[idx] * (1.f - m) + vs * m;
  if (do_tanh) o = tanhf(o);
  out[idx] = o;
}

// ---------------- launch ----------------
static inline unsigned gdiv(long total) { return (unsigned)((total + 255) / 256); }

extern "C" void kernel_launch(void* const* d_in, const int* in_sizes, int n_in,
                              void* d_out, int out_size, void* d_ws, size_t ws_size,
                              hipStream_t stream)
{
  (void)in_sizes; (void)n_in; (void)out_size; (void)ws_size;
  const float* sketch   = (const float*)d_in[0];
  const float* depth    = (const float*)d_in[1];
  const float* style    = (const float*)d_in[2];
  const float* enc1_w   = (const float*)d_in[3];
  const float* enc1_b   = (const float*)d_in[4];
  const float* enc2_w   = (const float*)d_in[5];
  const float* enc2_b   = (const float*)d_in[6];
  const float* enc3_w   = (const float*)d_in[7];
  const float* enc3_b   = (const float*)d_in[8];
  const float* se1_w    = (const float*)d_in[9];
  const float* se1_b    = (const float*)d_in[10];
  const float* se2_w    = (const float*)d_in[11];
  const float* se2_b    = (const float*)d_in[12];
  const float* se3_w    = (const float*)d_in[13];
  const float* se3_b    = (const float*)d_in[14];
  const float* sp1_w    = (const float*)d_in[15];
  const float* sp1_b    = (const float*)d_in[16];
  const float* sp2_w    = (const float*)d_in[17];
  const float* sp2_b    = (const float*)d_in[18];
  const float* sm_w     = (const float*)d_in[19];
  const float* sm_b     = (const float*)d_in[20];
  const float* attn_q_w = (const float*)d_in[21];
  const float* attn_q_b = (const float*)d_in[22];
  const float* attn_k_w = (const float*)d_in[23];
  const float* attn_k_b = (const float*)d_in[24];
  const float* attn_v_w = (const float*)d_in[25];
  const float* attn_v_b = (const float*)d_in[26];
  const float* attn_g   = (const float*)d_in[27];
  const float* bn_w     = (const float*)d_in[28];
  const float* bn_b     = (const float*)d_in[29];
  const float* dec3_w   = (const float*)d_in[30];
  const float* dec3_b   = (const float*)d_in[31];
  const float* dec2_w   = (const float*)d_in[32];
  const float* dec2_b   = (const float*)d_in[33];
  const float* dec1_w   = (const float*)d_in[34];
  const float* dec1_b   = (const float*)d_in[35];
  float* out = (float*)d_out;

  float* ws    = (float*)d_ws;
  float* e1    = ws + OFF_E1;
  float* e2    = ws + OFF_E2;
  float* e3a   = ws + OFF_E3A;
  float* e3b   = ws + OFF_E3B;
  float* big16 = ws + OFF_BIG16;   // also attn o_part (6 x 1M, spans into big8)
  float* big8  = ws + OFF_BIG8;
  float* b4    = ws + OFF_B4;
  float* vbuf  = ws + OFF_V;
  float* qbuf  = ws + OFF_Q;
  float* kbuf  = ws + OFF_K;
  float* pool  = ws + OFF_POOL;
  float* sf1   = ws + OFF_SF1;
  float* sf2   = ws + OFF_SF2;
  float* rowst = ws + OFF_ROW;
  float* d2lf  = ws + OFF_D2LF;    // head doubles as attn l_part
  float* pre   = ws + OFF_PRE;

  const int B = 4;

  // ---- stage 1: enc1 and se1 (independent) ----
  k_c3<1,1,0, 2, 256,256,1, 2, 16,16, 1,0,0><<<dim3(256, B, 1), 256, 0, stream>>>(
      sketch, depth, enc1_w, enc1_b, nullptr, e1);
  k_c3<3,0,0, 3, 256,256,1, 3, 16,16, 1,0,0><<<dim3(256, B, 1), 256, 0, stream>>>(
      style, nullptr, se1_w, se1_b, nullptr, big16);

  // ---- stage 2: enc2 + se2 merged; enc3 + se3 merged ----
  k_c4dual<16,2,32,8, 256,256, 128,2><<<dim3(64, B, 8), 256, 0, stream>>>(
      e1, enc2_w, enc2_b, e2, big16, se2_w, se2_b, big8);
  k_c4dual<32,2,64,4, 128,128, 64,4><<<dim3(16, B, 32), 256, 0, stream>>>(
      e2, enc3_w, enc3_b, e3a, big8, se3_w, se3_b, b4);

  // ---- line_filter(e3, 0.8): e3a -> e3b ----
  k_lf_rowstat<<<(B*64*64 + 3)/4, 256, 0, stream>>>(e3a, rowst, B*64*64, 64);
  k_lf_apply<<<gdiv((long)B*64*64*64), 256, 0, stream>>>(e3a, rowst, e3b, B*64, 64, 64, 0.8f, 0);

  // ---- style head ----
  k_pool8<<<gdiv(B*64*64), 256, 0, stream>>>(b4, pool, B, 64, 64, 64);
  k_fc_relu<<<(B*64 + 3)/4, 256, 0, stream>>>(pool, sp1_w, sp1_b, sf1, B, 4096, 64);
  k_fc_relu<<<(B*64 + 3)/4, 256, 0, stream>>>(sf1, sp2_w, sp2_b, sf2, B, 64, 64);

  // ---- style merge (+mix fused, bcast channels via wsum) ----
  k_wsum<<<B, 256, 0, stream>>>(sm_w, sf2, pool);
  k_c3<64,0,0, 128, 64,64,4, 8, 64,4, 1,1,1><<<dim3(16, B, 16), 256, 0, stream>>>(
      e3b, nullptr, sm_w, sm_b, pool, e3a);

  // ---- self-attention on e3a -> e3b (merged proj, uneven KV-split x6) ----
  k_qkvproj<<<dim3(64, 5), 256, 0, stream>>>(
      e3a, attn_q_w, attn_q_b, attn_k_w, attn_k_b, attn_v_w, attn_v_b,
      qbuf, kbuf, vbuf, 4096);
  k_fattn<<<dim3(32, B, 6), 256, 0, stream>>>(qbuf, kbuf, vbuf, big16, d2lf, 4096);
  k_attnfin<<<4096, 256, 0, stream>>>(big16, d2lf, e3a, attn_g, e3b);

  // ---- bottleneck + decoder ----
  k_c3<64,0,0, 64, 64,64,4, 8, 64,4, 1,0,0><<<dim3(16, B, 16), 256, 0, stream>>>(
      e3b, nullptr, bn_w, bn_b, nullptr, b4);
  k_ct<64,64,32,2, 64,64, 4,4><<<dim3(16, B, 16), 256, 0, stream>>>(b4, e3b, dec3_w, dec3_b, big8);
  k_ct<32,32,16,4, 128,128, 2,4><<<dim3(64, B, 4), 256, 0, stream>>>(big8, e2, dec2_w, dec2_b, big16);
  k_lf_rowstat<<<(B*16*256 + 3)/4, 256, 0, stream>>>(big16, rowst, B*16*256, 256);
  k_lf_apply<<<gdiv((long)B*16*256*256), 256, 0, stream>>>(big16, rowst, d2lf, B*16, 256, 256, 0.8f, 0);
  k_c3<16,16,0, 32, 256,256,1, 8, 3,3, 0,0,0><<<dim3(256, B, 1), 256, 0, stream>>>(
      d2lf, e1, dec1_w, dec1_b, nullptr, pre);
  k_lf_rowstat<<<(B*3*256 + 3)/4, 256, 0, stream>>>(pre, rowst, B*3*256, 256);
  k_lf_apply<<<gdiv((long)B*3*256*256), 256, 0, stream>>>(pre, rowst, out, B*3, 256, 256, 0.9f, 1);
}

// Round 15
// 835.949 us; speedup vs baseline: 1.0640x; 1.0640x over previous
//
#include <hip/hip_runtime.h>
#include <cstdint>
#include <cstddef>

// ---------------- workspace layout (floats) ----------------
static const size_t OFF_E1    = 0;         // [4,16,256,256]
static const size_t OFF_E2    = 4194304;   // [4,32,128,128]
static const size_t OFF_E3A   = 6291456;   // [4,64,64,64]
static const size_t OFF_E3B   = 7340032;   // [4,64,64,64]
static const size_t OFF_BIG16 = 8388608;   // s1 | attn o_part [6][4][64][4096] (spans big8) | d2raw
static const size_t OFF_BIG8  = 12582912;  // s2 then d3
static const size_t OFF_B4    = 14680064;  // s3 then bn-out
static const size_t OFF_V     = 15728640;  // vT [4,4096,64]
static const size_t OFF_Q     = 16777216;  // qT [4,4096,8]
static const size_t OFF_K     = 16908288;  // kC [4,8,4096]
static const size_t OFF_POOL  = 17039360;  // pool then wsum[4][64][9]
static const size_t OFF_SF1   = 17055744;
static const size_t OFF_SF2   = 17056000;
static const size_t OFF_ROW   = 17056256;
static const size_t OFF_D2LF  = 17072640;  // attn l_part [6][4][4096] | then [4,16,256,256]
static const size_t OFF_PRE   = 21266944;  // [4,3,256,256]

// ============== conv3x3 s1 p1, LDS-staged, multi-co per thread ==============
template<int C1, int C2, int BCAST2, int CIN_W, int W, int H, int ROWS,
         int CI_CH, int COUT, int CO_T, int RELU, int MIX, int WSUM>
__global__ __launch_bounds__(256) void k_c3(
    const float* __restrict__ in1, const float* __restrict__ in2,
    const float* __restrict__ w, const float* __restrict__ bias,
    const float* __restrict__ wsum, float* __restrict__ out)
{
  constexpr int CIN = C1 + C2;
  constexpr int PW = W + 4;
  constexpr int LR = ROWS + 2;
  __shared__ float lds[CI_CH * LR * PW];

  int tid = threadIdx.x;
  int tx = tid % W, ty = tid / W;
  int b = blockIdx.y;
  int co0 = blockIdx.z * CO_T;
  int oh0 = blockIdx.x * ROWS;
  int oh = oh0 + ty;

  float acc[CO_T];
#pragma unroll
  for (int i = 0; i < CO_T; ++i) acc[i] = bias[co0 + i];

  if (WSUM) {
    bool rv0 = oh - 1 >= 0, rv2 = oh + 1 < H;
    bool cv0 = tx - 1 >= 0, cv2 = tx + 1 < W;
    bool rv[3] = {rv0, true, rv2};
    bool cv[3] = {cv0, true, cv2};
    const float* wsp = wsum + ((long)b * COUT + co0) * 9;
#pragma unroll
    for (int co = 0; co < CO_T; ++co)
#pragma unroll
      for (int ky = 0; ky < 3; ++ky)
#pragma unroll
        for (int kx = 0; kx < 3; ++kx)
          acc[co] += (rv[ky] && cv[kx]) ? wsp[co * 9 + ky * 3 + kx] : 0.f;
  }

  for (int c0 = 0; c0 < CIN; c0 += CI_CH) {
    constexpr int TOTAL = CI_CH * LR * PW;
    for (int i = tid; i < TOTAL; i += 256) {
      int ci_l = i / (LR * PW);
      int rem = i % (LR * PW);
      int r = rem / PW, c = rem % PW;
      int ih = oh0 - 1 + r, iw = c - 1;
      int ci = c0 + ci_l;
      float v = 0.f;
      if ((unsigned)ih < (unsigned)H && (unsigned)iw < (unsigned)W) {
        if (ci < C1) v = in1[((long)(b * C1 + ci) * H + ih) * W + iw];
        else if (BCAST2) v = in2[b * C2 + ci - C1];
        else v = in2[((long)(b * C2 + ci - C1) * H + ih) * W + iw];
      }
      lds[i] = v;
    }
    __syncthreads();
#pragma unroll
    for (int ci_l = 0; ci_l < CI_CH; ++ci_l) {
      int ci = c0 + ci_l;
      float x[3][3];
#pragma unroll
      for (int ky = 0; ky < 3; ++ky)
#pragma unroll
        for (int kx = 0; kx < 3; ++kx)
          x[ky][kx] = lds[ci_l * (LR * PW) + (ty + ky) * PW + tx + kx];
      const float* wb = w + (long)ci * 9;
#pragma unroll
      for (int co = 0; co < CO_T; ++co) {
        const float* wp = wb + (long)(co0 + co) * CIN_W * 9;
#pragma unroll
        for (int ky = 0; ky < 3; ++ky)
#pragma unroll
          for (int kx = 0; kx < 3; ++kx)
            acc[co] += wp[ky * 3 + kx] * x[ky][kx];
      }
    }
    __syncthreads();
  }

#pragma unroll
  for (int co = 0; co < CO_T; ++co) {
    float a = acc[co];
    if (RELU) a = fmaxf(a, 0.f);
    if (MIX) {
      float m = in1[((long)(b * C1 + co0 + co) * H + oh) * W + tx];
      a = 0.99f * m + 0.01f * a;
    }
    out[((long)(b * COUT + co0 + co) * H + oh) * W + tx] = a;
  }
}

// ====== conv4x4 s2 p1 + relu, dual-branch merged launch, dbuf pipeline ======
template<int CIN, int CI_CH, int COUT, int CO_T, int WIN, int HIN, int TW, int TH>
__global__ __launch_bounds__(256) void k_c4dual(
    const float* __restrict__ in1, const float* __restrict__ w1,
    const float* __restrict__ b1, float* __restrict__ out1,
    const float* __restrict__ in2, const float* __restrict__ w2,
    const float* __restrict__ b2, float* __restrict__ out2)
{
  constexpr int ZSPLIT = COUT / CO_T;
  constexpr int Wo = WIN / 2, Ho = HIN / 2;
  constexpr int PW = 2 * TW + 4;
  constexpr int LR = 2 * TH + 2;
  constexpr int TOTAL = CI_CH * LR * PW;
  constexpr int SITER = (TOTAL + 255) / 256;
  constexpr int WTOT = CIN * CO_T * 16;
  __shared__ float lin[2][TOTAL];
  __shared__ float w_s[WTOT];

  int tid = threadIdx.x;
  int tx = tid % TW, ty = tid / TW;
  int b = blockIdx.y;
  int z = blockIdx.z;
  const float* in; const float* w; const float* bias; float* out; int co0;
  if (z < ZSPLIT) { in = in1; w = w1; bias = b1; out = out1; co0 = z * CO_T; }
  else            { in = in2; w = w2; bias = b2; out = out2; co0 = (z - ZSPLIT) * CO_T; }
  int oh0 = blockIdx.x * TH;
  int oh = oh0 + ty;
  int R0 = 2 * oh0 - 1;

  for (int i = tid; i < WTOT; i += 256) {
    int t = i & 15, co = (i >> 4) % CO_T, ci = (i >> 4) / CO_T;
    w_s[i] = w[((long)(co0 + co) * CIN + ci) * 16 + t];
  }

  float acc[CO_T];
#pragma unroll
  for (int i = 0; i < CO_T; ++i) acc[i] = bias[co0 + i];

  float sreg[SITER];
#pragma unroll
  for (int it = 0; it < SITER; ++it) {
    int i = tid + it * 256;
    float v = 0.f;
    if (i < TOTAL) {
      int ci_l = i / (LR * PW);
      int rem = i % (LR * PW);
      int r = rem / PW, c = rem % PW;
      int ih = R0 + r, iw = c - 1;
      if ((unsigned)ih < (unsigned)HIN && (unsigned)iw < (unsigned)WIN)
        v = in[((long)(b * CIN + ci_l) * HIN + ih) * WIN + iw];
    }
    sreg[it] = v;
  }
#pragma unroll
  for (int it = 0; it < SITER; ++it) {
    int i = tid + it * 256;
    if (i < TOTAL) lin[0][i] = sreg[it];
  }

  int cur = 0;
  for (int c0 = 0; c0 < CIN; c0 += CI_CH) {
    bool has_next = (c0 + CI_CH < CIN);
    if (has_next) {
#pragma unroll
      for (int it = 0; it < SITER; ++it) {
        int i = tid + it * 256;
        float v = 0.f;
        if (i < TOTAL) {
          int ci_l = i / (LR * PW);
          int rem = i % (LR * PW);
          int r = rem / PW, c = rem % PW;
          int ih = R0 + r, iw = c - 1;
          if ((unsigned)ih < (unsigned)HIN && (unsigned)iw < (unsigned)WIN)
            v = in[((long)(b * CIN + c0 + CI_CH + ci_l) * HIN + ih) * WIN + iw];
        }
        sreg[it] = v;
      }
    }
    __syncthreads();
#pragma unroll
    for (int ci_l = 0; ci_l < CI_CH; ++ci_l) {
      int ci = c0 + ci_l;
      float x[4][4];
#pragma unroll
      for (int ky = 0; ky < 4; ++ky)
#pragma unroll
        for (int kx = 0; kx < 4; ++kx)
          x[ky][kx] = lin[cur][ci_l * (LR * PW) + (2 * ty + ky) * PW + 2 * tx + kx];
#pragma unroll
      for (int co = 0; co < CO_T; ++co) {
        const float* wp = &w_s[(ci * CO_T + co) * 16];
        float4 wa = *(const float4*)(wp);
        float4 wb = *(const float4*)(wp + 4);
        float4 wc = *(const float4*)(wp + 8);
        float4 wd = *(const float4*)(wp + 12);
        acc[co] += wa.x*x[0][0] + wa.y*x[0][1] + wa.z*x[0][2] + wa.w*x[0][3]
                 + wb.x*x[1][0] + wb.y*x[1][1] + wb.z*x[1][2] + wb.w*x[1][3]
                 + wc.x*x[2][0] + wc.y*x[2][1] + wc.z*x[2][2] + wc.w*x[2][3]
                 + wd.x*x[3][0] + wd.y*x[3][1] + wd.z*x[3][2] + wd.w*x[3][3];
      }
    }
    if (has_next) {
#pragma unroll
      for (int it = 0; it < SITER; ++it) {
        int i = tid + it * 256;
        if (i < TOTAL) lin[cur ^ 1][i] = sreg[it];
      }
    }
    cur ^= 1;
  }

#pragma unroll
  for (int co = 0; co < CO_T; ++co)
    out[((long)(b * COUT + co0 + co) * Ho + oh) * Wo + tx] = fmaxf(acc[co], 0.f);
}

// ============== convT 4x4 s2 p1 + relu, w_s in LDS, dbuf pipeline ===========
template<int C1, int C2, int COUT, int CO_T, int WIN, int HIN, int TPR, int CI_CH>
__global__ __launch_bounds__(256) void k_ct(
    const float* __restrict__ in1, const float* __restrict__ in2,
    const float* __restrict__ w, const float* __restrict__ bias,
    float* __restrict__ out)
{
  constexpr int CIN = C1 + C2;
  constexpr int Wo = 2 * WIN, Ho = 2 * HIN;
  constexpr int PW = WIN + 4;
  constexpr int LR = TPR + 2;
  constexpr int TOTAL = CI_CH * LR * PW;
  constexpr int SITER = (TOTAL + 255) / 256;
  constexpr int WTOT = CIN * CO_T * 16;
  __shared__ float lin[2][TOTAL];
  __shared__ float w_s[WTOT];

  int tid = threadIdx.x;
  int s = tid % WIN, dt = tid / WIN;
  int b = blockIdx.y;
  int co0 = blockIdx.z * CO_T;
  int t0 = blockIdx.x * TPR;
  int t = t0 + dt;

  for (int i = tid; i < WTOT; i += 256) {
    int tt = i & 15, co = (i >> 4) % CO_T, ci = (i >> 4) / CO_T;
    w_s[i] = w[((long)ci * COUT + co0 + co) * 16 + tt];
  }

  float aee[CO_T], aeo[CO_T], aoe[CO_T], aoo[CO_T];
#pragma unroll
  for (int i = 0; i < CO_T; ++i) {
    float bb = bias[co0 + i];
    aee[i] = bb; aeo[i] = bb; aoe[i] = bb; aoo[i] = bb;
  }

  float sreg[SITER];
#pragma unroll
  for (int it = 0; it < SITER; ++it) {
    int i = tid + it * 256;
    float v = 0.f;
    if (i < TOTAL) {
      int ci_l = i / (LR * PW);
      int rem = i % (LR * PW);
      int r = rem / PW, c = rem % PW;
      int ih = t0 - 1 + r, iw = c - 1;
      if ((unsigned)ih < (unsigned)HIN && (unsigned)iw < (unsigned)WIN) {
        v = (ci_l < C1) ? in1[((long)(b * C1 + ci_l) * HIN + ih) * WIN + iw]
                        : in2[((long)(b * C2 + ci_l - C1) * HIN + ih) * WIN + iw];
      }
    }
    sreg[it] = v;
  }
#pragma unroll
  for (int it = 0; it < SITER; ++it) {
    int i = tid + it * 256;
    if (i < TOTAL) lin[0][i] = sreg[it];
  }

  int cur = 0;
  for (int c0 = 0; c0 < CIN; c0 += CI_CH) {
    bool has_next = (c0 + CI_CH < CIN);
    if (has_next) {
#pragma unroll
      for (int it = 0; it < SITER; ++it) {
        int i = tid + it * 256;
        float v = 0.f;
        if (i < TOTAL) {
          int ci_l = i / (LR * PW);
          int rem = i % (LR * PW);
          int r = rem / PW, c = rem % PW;
          int ih = t0 - 1 + r, iw = c - 1;
          int ci = c0 + CI_CH + ci_l;
          if ((unsigned)ih < (unsigned)HIN && (unsigned)iw < (unsigned)WIN) {
            v = (ci < C1) ? in1[((long)(b * C1 + ci) * HIN + ih) * WIN + iw]
                          : in2[((long)(b * C2 + ci - C1) * HIN + ih) * WIN + iw];
          }
        }
        sreg[it] = v;
      }
    }
    __syncthreads();
#pragma unroll
    for (int ci_l = 0; ci_l < CI_CH; ++ci_l) {
      int ci = c0 + ci_l;
      float x[3][3];
#pragma unroll
      for (int r = 0; r < 3; ++r)
#pragma unroll
        for (int c = 0; c < 3; ++c)
          x[r][c] = lin[cur][ci_l * (LR * PW) + (dt + r) * PW + s + c];
#pragma unroll
      for (int co = 0; co < CO_T; ++co) {
        const float* wp = &w_s[(ci * CO_T + co) * 16];
        float4 wa = *(const float4*)(wp);
        float4 wb = *(const float4*)(wp + 4);
        float4 wc = *(const float4*)(wp + 8);
        float4 wd = *(const float4*)(wp + 12);
        aee[co] += wb.y * x[1][1] + wb.w * x[1][0] + wd.y * x[0][1] + wd.w * x[0][0];
        aeo[co] += wb.x * x[1][2] + wb.z * x[1][1] + wd.x * x[0][2] + wd.z * x[0][1];
        aoe[co] += wa.y * x[2][1] + wa.w * x[2][0] + wc.y * x[1][1] + wc.w * x[1][0];
        aoo[co] += wa.x * x[2][2] + wa.z * x[2][1] + wc.x * x[1][2] + wc.z * x[1][1];
      }
    }
    if (has_next) {
#pragma unroll
      for (int it = 0; it < SITER; ++it) {
        int i = tid + it * 256;
        if (i < TOTAL) lin[cur ^ 1][i] = sreg[it];
      }
    }
    cur ^= 1;
  }

#pragma unroll
  for (int co = 0; co < CO_T; ++co) {
    long base = ((long)(b * COUT + co0 + co) * Ho + 2 * t) * Wo + 2 * s;
    float2 r0; r0.x = fmaxf(aee[co], 0.f); r0.y = fmaxf(aeo[co], 0.f);
    float2 r1; r1.x = fmaxf(aoe[co], 0.f); r1.y = fmaxf(aoo[co], 0.f);
    *(float2*)(out + base) = r0;
    *(float2*)(out + base + Wo) = r1;
  }
}

// ============== wsum precompute for style-merge broadcast channels ==========
__global__ __launch_bounds__(256) void k_wsum(
    const float* __restrict__ w, const float* __restrict__ sf,
    float* __restrict__ wsum)
{
  int b = blockIdx.x;
  for (int i = threadIdx.x; i < 576; i += 256) {
    int co = i / 9, t = i % 9;
    float s = 0.f;
    for (int ci = 0; ci < 64; ++ci)
      s += w[((long)co * 128 + 64 + ci) * 9 + t] * sf[b * 64 + ci];
    wsum[((long)b * 64 + co) * 9 + t] = s;
  }
}

// ===== merged q/k/v projection: y<4 -> V quarter, y==4 -> Q+K ==============
__global__ __launch_bounds__(256) void k_qkvproj(
    const float* __restrict__ x,
    const float* __restrict__ wq, const float* __restrict__ bq,
    const float* __restrict__ wk, const float* __restrict__ bk,
    const float* __restrict__ wv, const float* __restrict__ bv,
    float* __restrict__ qT, float* __restrict__ kC,
    float* __restrict__ vT, int N)
{
  int idx = blockIdx.x * 256 + threadIdx.x;
  int n = idx % N, b = idx / N;
  const float* src = x + (long)b * 64 * N + n;
  if (blockIdx.y < 4) {
    int cq = blockIdx.y * 16;
    float va[16];
#pragma unroll
    for (int c = 0; c < 16; ++c) va[c] = bv[cq + c];
    for (int ci = 0; ci < 64; ++ci) {
      float xv = src[(long)ci * N];
#pragma unroll
      for (int c = 0; c < 16; ++c) va[c] += wv[(cq + c) * 64 + ci] * xv;
    }
    float* vo = vT + ((long)b * N + n) * 64 + cq;
#pragma unroll
    for (int c = 0; c < 16; c += 4) {
      float4 o; o.x = va[c]; o.y = va[c+1]; o.z = va[c+2]; o.w = va[c+3];
      *(float4*)(vo + c) = o;
    }
  } else {
    float qa[8], ka[8];
#pragma unroll
    for (int c = 0; c < 8; ++c) { qa[c] = bq[c]; ka[c] = bk[c]; }
    for (int ci = 0; ci < 64; ++ci) {
      float xv = src[(long)ci * N];
#pragma unroll
      for (int c = 0; c < 8; ++c) {
        qa[c] += wq[c * 64 + ci] * xv;
        ka[c] += wk[c * 64 + ci] * xv;
      }
    }
    float* qo = qT + ((long)b * N + n) * 8;
#pragma unroll
    for (int c = 0; c < 8; ++c) qo[c] = qa[c];
#pragma unroll
    for (int c = 0; c < 8; ++c) kC[((long)b * 8 + c) * N + n] = ka[c];
  }
}

// ====== flash attention v6 (proven): TQ=128, 4q x 8c, v_s staged, x6 split ==
__global__ __launch_bounds__(256) void k_fattn(
    const float* __restrict__ qT, const float* __restrict__ kC,
    const float* __restrict__ vT, float* __restrict__ o_part,
    float* __restrict__ l_part, int N)
{
  __shared__ float k_s[8][68];
  __shared__ float v_s[64 * 64];     // [m][c]
  __shared__ float p_s[64 * 132];    // [m][q] stride 132; reused as o_sT[c][q]

  int tid = threadIdx.x;
  int n0 = blockIdx.x * 128;
  int b = blockIdx.y;
  int split = blockIdx.z;
  int qg = tid >> 3;   // 0..31
  int xg = tid & 7;    // 0..7

  int tstart = split * 10 + min(split, 4);
  int tcount = 10 + (split < 4 ? 1 : 0);

  float qv[4][8];
#pragma unroll
  for (int i = 0; i < 4; ++i) {
    const float4* qp = (const float4*)(qT + ((long)b * N + n0 + qg * 4 + i) * 8);
    float4 a = qp[0], c = qp[1];
    qv[i][0]=a.x; qv[i][1]=a.y; qv[i][2]=a.z; qv[i][3]=a.w;
    qv[i][4]=c.x; qv[i][5]=c.y; qv[i][6]=c.z; qv[i][7]=c.w;
  }

  float o[4][8];
#pragma unroll
  for (int i = 0; i < 4; ++i)
#pragma unroll
    for (int j = 0; j < 8; ++j) o[i][j] = 0.f;
  float l[4] = {0.f, 0.f, 0.f, 0.f};

  const float* kbase = kC + (long)b * 8 * N;
  const float* vbase = vT + (long)b * N * 64;

  for (int t = tstart; t < tstart + tcount; ++t) {
    int m0 = t * 64;
    float4 vr0, vr1, vr2, vr3;
    {
      const float4* vp = (const float4*)(vbase + (long)m0 * 64) + tid;
      vr0 = vp[0]; vr1 = vp[256]; vr2 = vp[512]; vr3 = vp[768];
    }
    {
      int kk = tid >> 5, seg = tid & 31;
      float2 kv2 = *(const float2*)(kbase + (long)kk * N + m0 + seg * 2);
      *(float2*)&k_s[kk][seg * 2] = kv2;
    }
    __syncthreads();   // (A) k_s ready; all waves done with prev p_s/v_s

    float s[4][8];
#pragma unroll
    for (int i = 0; i < 4; ++i)
#pragma unroll
      for (int j = 0; j < 8; ++j) s[i][j] = 0.f;
#pragma unroll
    for (int kk = 0; kk < 8; ++kk) {
      float4 ka = *(const float4*)&k_s[kk][xg * 8];
      float4 kb = *(const float4*)&k_s[kk][xg * 8 + 4];
#pragma unroll
      for (int i = 0; i < 4; ++i) {
        float q = qv[i][kk];
        s[i][0] += q * ka.x; s[i][1] += q * ka.y; s[i][2] += q * ka.z; s[i][3] += q * ka.w;
        s[i][4] += q * kb.x; s[i][5] += q * kb.y; s[i][6] += q * kb.z; s[i][7] += q * kb.w;
      }
    }
#pragma unroll
    for (int i = 0; i < 4; ++i) {
#pragma unroll
      for (int j = 0; j < 8; ++j) {
        s[i][j] = __expf(s[i][j]);
        l[i] += s[i][j];
      }
    }
#pragma unroll
    for (int j = 0; j < 8; ++j) {
      float4 w4; w4.x = s[0][j]; w4.y = s[1][j]; w4.z = s[2][j]; w4.w = s[3][j];
      *(float4*)&p_s[(xg * 8 + j) * 132 + qg * 4] = w4;
    }
    {
      float* vd = v_s + tid * 4;
      *(float4*)(vd +    0) = vr0;
      *(float4*)(vd + 1024) = vr1;
      *(float4*)(vd + 2048) = vr2;
      *(float4*)(vd + 3072) = vr3;
    }
    __syncthreads();   // (B) p_s + v_s ready

#pragma unroll 4
    for (int mm = 0; mm < 16; ++mm) {
#pragma unroll
      for (int j = 0; j < 4; ++j) {
        int m = mm * 4 + j;
        float4 pr = *(const float4*)&p_s[m * 132 + qg * 4];
        float4 va = *(const float4*)&v_s[m * 64 + xg * 8];
        float4 vb4 = *(const float4*)&v_s[m * 64 + xg * 8 + 4];
#pragma unroll
        for (int i = 0; i < 4; ++i) {
          float p = (i == 0) ? pr.x : (i == 1) ? pr.y : (i == 2) ? pr.z : pr.w;
          o[i][0] += p * va.x;  o[i][1] += p * va.y;
          o[i][2] += p * va.z;  o[i][3] += p * va.w;
          o[i][4] += p * vb4.x; o[i][5] += p * vb4.y;
          o[i][6] += p * vb4.z; o[i][7] += p * vb4.w;
        }
      }
    }
    // no 3rd barrier: next tile's barrier (A) orders p_s/v_s overwrites
  }

#pragma unroll
  for (int i = 0; i < 4; ++i) {
#pragma unroll
    for (int d = 1; d < 8; d <<= 1) l[i] += __shfl_xor(l[i], d);
  }

  __syncthreads();   // all waves done with final PV before p_s reuse
#pragma unroll
  for (int j = 0; j < 8; ++j) {
    float4 w4; w4.x = o[0][j]; w4.y = o[1][j]; w4.z = o[2][j]; w4.w = o[3][j];
    *(float4*)&p_s[(xg * 8 + j) * 132 + qg * 4] = w4;
  }
  __syncthreads();
  float* obase = o_part + (long)split * 1048576 + ((long)b * 64) * 4096 + n0;
  for (int idx = tid; idx < 2048; idx += 256) {
    int c = idx >> 5, q4 = (idx & 31) << 2;
    float4 v4 = *(const float4*)&p_s[c * 132 + q4];
    *(float4*)(obase + (long)c * 4096 + q4) = v4;
  }
  if (xg == 0) {
    float4 lw; lw.x = l[0]; lw.y = l[1]; lw.z = l[2]; lw.w = l[3];
    *(float4*)&l_part[((long)split * 4 + b) * 4096 + n0 + qg * 4] = lw;
  }
}

// ============== attention combine (6 partials): out = g*(Σo)/(Σl) + x =======
__global__ __launch_bounds__(256) void k_attnfin(
    const float* __restrict__ op, const float* __restrict__ lp,
    const float* __restrict__ xb, const float* __restrict__ gamma_p,
    float* __restrict__ outb)
{
  int idx = blockIdx.x * 256 + threadIdx.x;   // covers 4*64*4096 = 1048576
  int n = idx & 4095;
  int b = idx >> 18;
  float g = gamma_p[0];
  float o = op[idx] + op[idx + 1048576] + op[idx + 2097152]
          + op[idx + 3145728] + op[idx + 4194304] + op[idx + 5242880];
  const float* lb = lp + b * 4096 + n;
  float l = lb[0] + lb[16384] + lb[32768] + lb[49152] + lb[65536] + lb[81920];
  outb[idx] = g * o / l + xb[idx];
}

// ================= adaptive avg pool to 8x8 ================================
__global__ __launch_bounds__(256) void k_pool8(
    const float* __restrict__ in, float* __restrict__ out, int B, int C, int H, int W)
{
  int idx = blockIdx.x * 256 + threadIdx.x;
  int total = B * C * 64;
  if (idx >= total) return;
  int ow = idx & 7, oh = (idx >> 3) & 7;
  int c = (idx >> 6) % C, b = idx / (64 * C);
  int bh = H / 8, bw = W / 8;
  const float* src = in + ((long)(b * C + c)) * H * W;
  float s = 0.f;
  for (int y = 0; y < bh; ++y)
    for (int x = 0; x < bw; ++x)
      s += src[(oh * bh + y) * W + ow * bw + x];
  out[idx] = s / (float)(bh * bw);
}

// ================= fc + relu (wave per output) ==============================
__global__ __launch_bounds__(256) void k_fc_relu(
    const float* __restrict__ in, const float* __restrict__ w,
    const float* __restrict__ bias, float* __restrict__ out, int B, int K, int O)
{
  int gi = blockIdx.x * 4 + (threadIdx.x >> 6);
  int lane = threadIdx.x & 63;
  if (gi >= B * O) return;
  int b = gi / O, o = gi % O;
  const float* x = in + (long)b * K;
  const float* wp = w + (long)o * K;
  float s = 0.f;
  for (int i = lane; i < K; i += 64) s += x[i] * wp[i];
#pragma unroll
  for (int d = 1; d < 64; d <<= 1) s += __shfl_xor(s, d);
  if (lane == 0) out[gi] = fmaxf(s + bias[o], 0.f);
}

// ================= line filter: per-row std -> sigmoid mask =================
__global__ __launch_bounds__(256) void k_lf_rowstat(
    const float* __restrict__ x, float* __restrict__ mask_raw, int rows, int W)
{
  int row = blockIdx.x * 4 + (threadIdx.x >> 6);
  int lane = threadIdx.x & 63;
  if (row >= rows) return;
  const float* p = x + (long)row * W;
  float s = 0.f;
  for (int i = lane; i < W; i += 64) s += p[i];
#pragma unroll
  for (int d = 1; d < 64; d <<= 1) s += __shfl_xor(s, d);
  float mean = s / (float)W;
  float v = 0.f;
  for (int i = lane; i < W; i += 64) { float t = p[i] - mean; v += t * t; }
#pragma unroll
  for (int d = 1; d < 64; d <<= 1) v += __shfl_xor(v, d);
  float stdv = sqrtf(v / (float)(W - 1));
  float mask = 1.f / (1.f + __expf(-(0.05f - stdv) * 10.f));
  if (lane == 0) mask_raw[row] = mask;
}

// ============ line filter apply, float4-vectorized (+optional tanh) =========
__global__ __launch_bounds__(256) void k_lf_apply4(
    const float* __restrict__ x, const float* __restrict__ mask_raw,
    float* __restrict__ out, int BC, int H, int W, float strength, int do_tanh)
{
  long idx = (long)blockIdx.x * 256 + threadIdx.x;   // one float4 per thread
  int wq = W >> 2;
  long total = (long)BC * H * wq;
  if (idx >= total) return;
  int w4 = (int)(idx % wq);
  int h = (int)((idx / wq) % H);
  int bc = (int)(idx / ((long)wq * H));
  const float* px = x + (long)bc * H * W + w4 * 4;
  const float* pm = mask_raw + (long)bc * H;
  float4 vs; vs.x = 0.f; vs.y = 0.f; vs.z = 0.f; vs.w = 0.f;
  float mb = 0.f;
#pragma unroll
  for (int d = -2; d <= 2; ++d) {
    int hh = h + d; hh = hh < 0 ? 0 : (hh >= H ? H - 1 : hh);
    float4 t = *(const float4*)(px + (long)hh * W);
    vs.x += t.x; vs.y += t.y; vs.z += t.z; vs.w += t.w;
    mb += pm[hh];
  }
  float m = mb * 0.2f * strength;
  float om = 1.f - m;
  float ms = m * 0.2f;
  float4 xv = *(const float4*)(px + (long)h * W);
  float4 r;
  r.x = xv.x * om + vs.x * ms;
  r.y = xv.y * om + vs.y * ms;
  r.z = xv.z * om + vs.z * ms;
  r.w = xv.w * om + vs.w * ms;
  if (do_tanh) {
    r.x = tanhf(r.x); r.y = tanhf(r.y); r.z = tanhf(r.z); r.w = tanhf(r.w);
  }
  *(float4*)(out + (long)bc * H * W + (long)h * W + w4 * 4) = r;
}

// ---------------- launch ----------------
static inline unsigned gdiv(long total) { return (unsigned)((total + 255) / 256); }

extern "C" void kernel_launch(void* const* d_in, const int* in_sizes, int n_in,
                              void* d_out, int out_size, void* d_ws, size_t ws_size,
                              hipStream_t stream)
{
  (void)in_sizes; (void)n_in; (void)out_size; (void)ws_size;
  const float* sketch   = (const float*)d_in[0];
  const float* depth    = (const float*)d_in[1];
  const float* style    = (const float*)d_in[2];
  const float* enc1_w   = (const float*)d_in[3];
  const float* enc1_b   = (const float*)d_in[4];
  const float* enc2_w   = (const float*)d_in[5];
  const float* enc2_b   = (const float*)d_in[6];
  const float* enc3_w   = (const float*)d_in[7];
  const float* enc3_b   = (const float*)d_in[8];
  const float* se1_w    = (const float*)d_in[9];
  const float* se1_b    = (const float*)d_in[10];
  const float* se2_w    = (const float*)d_in[11];
  const float* se2_b    = (const float*)d_in[12];
  const float* se3_w    = (const float*)d_in[13];
  const float* se3_b    = (const float*)d_in[14];
  const float* sp1_w    = (const float*)d_in[15];
  const float* sp1_b    = (const float*)d_in[16];
  const float* sp2_w    = (const float*)d_in[17];
  const float* sp2_b    = (const float*)d_in[18];
  const float* sm_w     = (const float*)d_in[19];
  const float* sm_b     = (const float*)d_in[20];
  const float* attn_q_w = (const float*)d_in[21];
  const float* attn_q_b = (const float*)d_in[22];
  const float* attn_k_w = (const float*)d_in[23];
  const float* attn_k_b = (const float*)d_in[24];
  const float* attn_v_w = (const float*)d_in[25];
  const float* attn_v_b = (const float*)d_in[26];
  const float* attn_g   = (const float*)d_in[27];
  const float* bn_w     = (const float*)d_in[28];
  const float* bn_b     = (const float*)d_in[29];
  const float* dec3_w   = (const float*)d_in[30];
  const float* dec3_b   = (const float*)d_in[31];
  const float* dec2_w   = (const float*)d_in[32];
  const float* dec2_b   = (const float*)d_in[33];
  const float* dec1_w   = (const float*)d_in[34];
  const float* dec1_b   = (const float*)d_in[35];
  float* out = (float*)d_out;

  float* ws    = (float*)d_ws;
  float* e1    = ws + OFF_E1;
  float* e2    = ws + OFF_E2;
  float* e3a   = ws + OFF_E3A;
  float* e3b   = ws + OFF_E3B;
  float* big16 = ws + OFF_BIG16;   // also attn o_part (6 x 1M, spans into big8)
  float* big8  = ws + OFF_BIG8;
  float* b4    = ws + OFF_B4;
  float* vbuf  = ws + OFF_V;
  float* qbuf  = ws + OFF_Q;
  float* kbuf  = ws + OFF_K;
  float* pool  = ws + OFF_POOL;
  float* sf1   = ws + OFF_SF1;
  float* sf2   = ws + OFF_SF2;
  float* rowst = ws + OFF_ROW;
  float* d2lf  = ws + OFF_D2LF;    // head doubles as attn l_part
  float* pre   = ws + OFF_PRE;

  const int B = 4;

  // ---- stage 1: enc1 and se1 (independent) ----
  k_c3<1,1,0, 2, 256,256,1, 2, 16,16, 1,0,0><<<dim3(256, B, 1), 256, 0, stream>>>(
      sketch, depth, enc1_w, enc1_b, nullptr, e1);
  k_c3<3,0,0, 3, 256,256,1, 3, 16,16, 1,0,0><<<dim3(256, B, 1), 256, 0, stream>>>(
      style, nullptr, se1_w, se1_b, nullptr, big16);

  // ---- stage 2: enc2 + se2 merged; enc3 + se3 merged ----
  k_c4dual<16,2,32,8, 256,256, 128,2><<<dim3(64, B, 8), 256, 0, stream>>>(
      e1, enc2_w, enc2_b, e2, big16, se2_w, se2_b, big8);
  k_c4dual<32,2,64,4, 128,128, 64,4><<<dim3(16, B, 32), 256, 0, stream>>>(
      e2, enc3_w, enc3_b, e3a, big8, se3_w, se3_b, b4);

  // ---- line_filter(e3, 0.8): e3a -> e3b ----
  k_lf_rowstat<<<(B*64*64 + 3)/4, 256, 0, stream>>>(e3a, rowst, B*64*64, 64);
  k_lf_apply4<<<gdiv((long)B*64*64*16), 256, 0, stream>>>(e3a, rowst, e3b, B*64, 64, 64, 0.8f, 0);

  // ---- style head ----
  k_pool8<<<gdiv(B*64*64), 256, 0, stream>>>(b4, pool, B, 64, 64, 64);
  k_fc_relu<<<(B*64 + 3)/4, 256, 0, stream>>>(pool, sp1_w, sp1_b, sf1, B, 4096, 64);
  k_fc_relu<<<(B*64 + 3)/4, 256, 0, stream>>>(sf1, sp2_w, sp2_b, sf2, B, 64, 64);

  // ---- style merge (+mix fused, bcast channels via wsum) ----
  k_wsum<<<B, 256, 0, stream>>>(sm_w, sf2, pool);
  k_c3<64,0,0, 128, 64,64,4, 8, 64,4, 1,1,1><<<dim3(16, B, 16), 256, 0, stream>>>(
      e3b, nullptr, sm_w, sm_b, pool, e3a);

  // ---- self-attention on e3a -> e3b (merged proj, uneven KV-split x6) ----
  k_qkvproj<<<dim3(64, 5), 256, 0, stream>>>(
      e3a, attn_q_w, attn_q_b, attn_k_w, attn_k_b, attn_v_w, attn_v_b,
      qbuf, kbuf, vbuf, 4096);
  k_fattn<<<dim3(32, B, 6), 256, 0, stream>>>(qbuf, kbuf, vbuf, big16, d2lf, 4096);
  k_attnfin<<<4096, 256, 0, stream>>>(big16, d2lf, e3a, attn_g, e3b);

  // ---- bottleneck + decoder ----
  k_c3<64,0,0, 64, 64,64,4, 8, 64,4, 1,0,0><<<dim3(16, B, 16), 256, 0, stream>>>(
      e3b, nullptr, bn_w, bn_b, nullptr, b4);
  k_ct<64,64,32,2, 64,64, 4,4><<<dim3(16, B, 16), 256, 0, stream>>>(b4, e3b, dec3_w, dec3_b, big8);
  k_ct<32,32,16,4, 128,128, 2,4><<<dim3(64, B, 4), 256, 0, stream>>>(big8, e2, dec2_w, dec2_b, big16);
  k_lf_rowstat<<<(B*16*256 + 3)/4, 256, 0, stream>>>(big16, rowst, B*16*256, 256);
  k_lf_apply4<<<gdiv((long)B*16*256*64), 256, 0, stream>>>(big16, rowst, d2lf, B*16, 256, 256, 0.8f, 0);
  k_c3<16,16,0, 32, 256,256,1, 8, 3,3, 0,0,0><<<dim3(256, B, 1), 256, 0, stream>>>(
      d2lf, e1, dec1_w, dec1_b, nullptr, pre);
  k_lf_rowstat<<<(B*3*256 + 3)/4, 256, 0, stream>>>(pre, rowst, B*3*256, 256);
  k_lf_apply4<<<gdiv((long)B*3*256*64), 256, 0, stream>>>(pre, rowst, out, B*3, 256, 256, 0.9f, 1);
}

// Round 16
// 827.763 us; speedup vs baseline: 1.0745x; 1.0099x over previous
//
#include <hip/hip_runtime.h>
#include <cstdint>
#include <cstddef>

// ---------------- workspace layout (floats) ----------------
static const size_t OFF_E1    = 0;         // [4,16,256,256]
static const size_t OFF_E2    = 4194304;   // [4,32,128,128]
static const size_t OFF_E3A   = 6291456;   // [4,64,64,64]
static const size_t OFF_E3B   = 7340032;   // [4,64,64,64]
static const size_t OFF_BIG16 = 8388608;   // s1 | attn o_part [6][4][64][4096] (spans big8) | d2raw
static const size_t OFF_BIG8  = 12582912;  // s2 then d3
static const size_t OFF_B4    = 14680064;  // s3 then bn-out
static const size_t OFF_V     = 15728640;  // vT [4,4096,64]
static const size_t OFF_Q     = 16777216;  // qT [4,4096,8]
static const size_t OFF_K     = 16908288;  // kC [4,8,4096]
static const size_t OFF_POOL  = 17039360;  // pool then wsum[4][64][9]
static const size_t OFF_SF1   = 17055744;
static const size_t OFF_SF2   = 17056000;
static const size_t OFF_ROW   = 17056256;
static const size_t OFF_D2LF  = 17072640;  // attn l_part [6][4][4096] | then [4,16,256,256]
static const size_t OFF_PRE   = 21266944;  // [4,3,256,256]

// ============== conv3x3 s1 p1, LDS-staged, multi-co per thread ==============
template<int C1, int C2, int BCAST2, int CIN_W, int W, int H, int ROWS,
         int CI_CH, int COUT, int CO_T, int RELU, int MIX, int WSUM>
__global__ __launch_bounds__(256) void k_c3(
    const float* __restrict__ in1, const float* __restrict__ in2,
    const float* __restrict__ w, const float* __restrict__ bias,
    const float* __restrict__ wsum, float* __restrict__ out)
{
  constexpr int CIN = C1 + C2;
  constexpr int PW = W + 4;
  constexpr int LR = ROWS + 2;
  __shared__ float lds[CI_CH * LR * PW];

  int tid = threadIdx.x;
  int tx = tid % W, ty = tid / W;
  int b = blockIdx.y;
  int co0 = blockIdx.z * CO_T;
  int oh0 = blockIdx.x * ROWS;
  int oh = oh0 + ty;

  float acc[CO_T];
#pragma unroll
  for (int i = 0; i < CO_T; ++i) acc[i] = bias[co0 + i];

  if (WSUM) {
    bool rv0 = oh - 1 >= 0, rv2 = oh + 1 < H;
    bool cv0 = tx - 1 >= 0, cv2 = tx + 1 < W;
    bool rv[3] = {rv0, true, rv2};
    bool cv[3] = {cv0, true, cv2};
    const float* wsp = wsum + ((long)b * COUT + co0) * 9;
#pragma unroll
    for (int co = 0; co < CO_T; ++co)
#pragma unroll
      for (int ky = 0; ky < 3; ++ky)
#pragma unroll
        for (int kx = 0; kx < 3; ++kx)
          acc[co] += (rv[ky] && cv[kx]) ? wsp[co * 9 + ky * 3 + kx] : 0.f;
  }

  for (int c0 = 0; c0 < CIN; c0 += CI_CH) {
    constexpr int TOTAL = CI_CH * LR * PW;
    for (int i = tid; i < TOTAL; i += 256) {
      int ci_l = i / (LR * PW);
      int rem = i % (LR * PW);
      int r = rem / PW, c = rem % PW;
      int ih = oh0 - 1 + r, iw = c - 1;
      int ci = c0 + ci_l;
      float v = 0.f;
      if ((unsigned)ih < (unsigned)H && (unsigned)iw < (unsigned)W) {
        if (ci < C1) v = in1[((long)(b * C1 + ci) * H + ih) * W + iw];
        else if (BCAST2) v = in2[b * C2 + ci - C1];
        else v = in2[((long)(b * C2 + ci - C1) * H + ih) * W + iw];
      }
      lds[i] = v;
    }
    __syncthreads();
#pragma unroll
    for (int ci_l = 0; ci_l < CI_CH; ++ci_l) {
      int ci = c0 + ci_l;
      float x[3][3];
#pragma unroll
      for (int ky = 0; ky < 3; ++ky)
#pragma unroll
        for (int kx = 0; kx < 3; ++kx)
          x[ky][kx] = lds[ci_l * (LR * PW) + (ty + ky) * PW + tx + kx];
      const float* wb = w + (long)ci * 9;
#pragma unroll
      for (int co = 0; co < CO_T; ++co) {
        const float* wp = wb + (long)(co0 + co) * CIN_W * 9;
#pragma unroll
        for (int ky = 0; ky < 3; ++ky)
#pragma unroll
          for (int kx = 0; kx < 3; ++kx)
            acc[co] += wp[ky * 3 + kx] * x[ky][kx];
      }
    }
    __syncthreads();
  }

#pragma unroll
  for (int co = 0; co < CO_T; ++co) {
    float a = acc[co];
    if (RELU) a = fmaxf(a, 0.f);
    if (MIX) {
      float m = in1[((long)(b * C1 + co0 + co) * H + oh) * W + tx];
      a = 0.99f * m + 0.01f * a;
    }
    out[((long)(b * COUT + co0 + co) * H + oh) * W + tx] = a;
  }
}

// ====== conv4x4 s2 p1 + relu, dual-branch merged launch, dbuf pipeline ======
template<int CIN, int CI_CH, int COUT, int CO_T, int WIN, int HIN, int TW, int TH>
__global__ __launch_bounds__(256) void k_c4dual(
    const float* __restrict__ in1, const float* __restrict__ w1,
    const float* __restrict__ b1, float* __restrict__ out1,
    const float* __restrict__ in2, const float* __restrict__ w2,
    const float* __restrict__ b2, float* __restrict__ out2)
{
  constexpr int ZSPLIT = COUT / CO_T;
  constexpr int Wo = WIN / 2, Ho = HIN / 2;
  constexpr int PW = 2 * TW + 4;
  constexpr int LR = 2 * TH + 2;
  constexpr int TOTAL = CI_CH * LR * PW;
  constexpr int SITER = (TOTAL + 255) / 256;
  constexpr int WTOT = CIN * CO_T * 16;
  __shared__ float lin[2][TOTAL];
  __shared__ float w_s[WTOT];

  int tid = threadIdx.x;
  int tx = tid % TW, ty = tid / TW;
  int b = blockIdx.y;
  int z = blockIdx.z;
  const float* in; const float* w; const float* bias; float* out; int co0;
  if (z < ZSPLIT) { in = in1; w = w1; bias = b1; out = out1; co0 = z * CO_T; }
  else            { in = in2; w = w2; bias = b2; out = out2; co0 = (z - ZSPLIT) * CO_T; }
  int oh0 = blockIdx.x * TH;
  int oh = oh0 + ty;
  int R0 = 2 * oh0 - 1;

  for (int i = tid; i < WTOT; i += 256) {
    int t = i & 15, co = (i >> 4) % CO_T, ci = (i >> 4) / CO_T;
    w_s[i] = w[((long)(co0 + co) * CIN + ci) * 16 + t];
  }

  float acc[CO_T];
#pragma unroll
  for (int i = 0; i < CO_T; ++i) acc[i] = bias[co0 + i];

  float sreg[SITER];
#pragma unroll
  for (int it = 0; it < SITER; ++it) {
    int i = tid + it * 256;
    float v = 0.f;
    if (i < TOTAL) {
      int ci_l = i / (LR * PW);
      int rem = i % (LR * PW);
      int r = rem / PW, c = rem % PW;
      int ih = R0 + r, iw = c - 1;
      if ((unsigned)ih < (unsigned)HIN && (unsigned)iw < (unsigned)WIN)
        v = in[((long)(b * CIN + ci_l) * HIN + ih) * WIN + iw];
    }
    sreg[it] = v;
  }
#pragma unroll
  for (int it = 0; it < SITER; ++it) {
    int i = tid + it * 256;
    if (i < TOTAL) lin[0][i] = sreg[it];
  }

  int cur = 0;
  for (int c0 = 0; c0 < CIN; c0 += CI_CH) {
    bool has_next = (c0 + CI_CH < CIN);
    if (has_next) {
#pragma unroll
      for (int it = 0; it < SITER; ++it) {
        int i = tid + it * 256;
        float v = 0.f;
        if (i < TOTAL) {
          int ci_l = i / (LR * PW);
          int rem = i % (LR * PW);
          int r = rem / PW, c = rem % PW;
          int ih = R0 + r, iw = c - 1;
          if ((unsigned)ih < (unsigned)HIN && (unsigned)iw < (unsigned)WIN)
            v = in[((long)(b * CIN + c0 + CI_CH + ci_l) * HIN + ih) * WIN + iw];
        }
        sreg[it] = v;
      }
    }
    __syncthreads();
#pragma unroll
    for (int ci_l = 0; ci_l < CI_CH; ++ci_l) {
      int ci = c0 + ci_l;
      float x[4][4];
#pragma unroll
      for (int ky = 0; ky < 4; ++ky)
#pragma unroll
        for (int kx = 0; kx < 4; ++kx)
          x[ky][kx] = lin[cur][ci_l * (LR * PW) + (2 * ty + ky) * PW + 2 * tx + kx];
#pragma unroll
      for (int co = 0; co < CO_T; ++co) {
        const float* wp = &w_s[(ci * CO_T + co) * 16];
        float4 wa = *(const float4*)(wp);
        float4 wb = *(const float4*)(wp + 4);
        float4 wc = *(const float4*)(wp + 8);
        float4 wd = *(const float4*)(wp + 12);
        acc[co] += wa.x*x[0][0] + wa.y*x[0][1] + wa.z*x[0][2] + wa.w*x[0][3]
                 + wb.x*x[1][0] + wb.y*x[1][1] + wb.z*x[1][2] + wb.w*x[1][3]
                 + wc.x*x[2][0] + wc.y*x[2][1] + wc.z*x[2][2] + wc.w*x[2][3]
                 + wd.x*x[3][0] + wd.y*x[3][1] + wd.z*x[3][2] + wd.w*x[3][3];
      }
    }
    if (has_next) {
#pragma unroll
      for (int it = 0; it < SITER; ++it) {
        int i = tid + it * 256;
        if (i < TOTAL) lin[cur ^ 1][i] = sreg[it];
      }
    }
    cur ^= 1;
  }

#pragma unroll
  for (int co = 0; co < CO_T; ++co)
    out[((long)(b * COUT + co0 + co) * Ho + oh) * Wo + tx] = fmaxf(acc[co], 0.f);
}

// ============== convT 4x4 s2 p1 + relu, w_s in LDS, dbuf pipeline ===========
template<int C1, int C2, int COUT, int CO_T, int WIN, int HIN, int TPR, int CI_CH>
__global__ __launch_bounds__(256) void k_ct(
    const float* __restrict__ in1, const float* __restrict__ in2,
    const float* __restrict__ w, const float* __restrict__ bias,
    float* __restrict__ out)
{
  constexpr int CIN = C1 + C2;
  constexpr int Wo = 2 * WIN, Ho = 2 * HIN;
  constexpr int PW = WIN + 4;
  constexpr int LR = TPR + 2;
  constexpr int TOTAL = CI_CH * LR * PW;
  constexpr int SITER = (TOTAL + 255) / 256;
  constexpr int WTOT = CIN * CO_T * 16;
  __shared__ float lin[2][TOTAL];
  __shared__ float w_s[WTOT];

  int tid = threadIdx.x;
  int s = tid % WIN, dt = tid / WIN;
  int b = blockIdx.y;
  int co0 = blockIdx.z * CO_T;
  int t0 = blockIdx.x * TPR;
  int t = t0 + dt;

  for (int i = tid; i < WTOT; i += 256) {
    int tt = i & 15, co = (i >> 4) % CO_T, ci = (i >> 4) / CO_T;
    w_s[i] = w[((long)ci * COUT + co0 + co) * 16 + tt];
  }

  float aee[CO_T], aeo[CO_T], aoe[CO_T], aoo[CO_T];
#pragma unroll
  for (int i = 0; i < CO_T; ++i) {
    float bb = bias[co0 + i];
    aee[i] = bb; aeo[i] = bb; aoe[i] = bb; aoo[i] = bb;
  }

  float sreg[SITER];
#pragma unroll
  for (int it = 0; it < SITER; ++it) {
    int i = tid + it * 256;
    float v = 0.f;
    if (i < TOTAL) {
      int ci_l = i / (LR * PW);
      int rem = i % (LR * PW);
      int r = rem / PW, c = rem % PW;
      int ih = t0 - 1 + r, iw = c - 1;
      if ((unsigned)ih < (unsigned)HIN && (unsigned)iw < (unsigned)WIN) {
        v = (ci_l < C1) ? in1[((long)(b * C1 + ci_l) * HIN + ih) * WIN + iw]
                        : in2[((long)(b * C2 + ci_l - C1) * HIN + ih) * WIN + iw];
      }
    }
    sreg[it] = v;
  }
#pragma unroll
  for (int it = 0; it < SITER; ++it) {
    int i = tid + it * 256;
    if (i < TOTAL) lin[0][i] = sreg[it];
  }

  int cur = 0;
  for (int c0 = 0; c0 < CIN; c0 += CI_CH) {
    bool has_next = (c0 + CI_CH < CIN);
    if (has_next) {
#pragma unroll
      for (int it = 0; it < SITER; ++it) {
        int i = tid + it * 256;
        float v = 0.f;
        if (i < TOTAL) {
          int ci_l = i / (LR * PW);
          int rem = i % (LR * PW);
          int r = rem / PW, c = rem % PW;
          int ih = t0 - 1 + r, iw = c - 1;
          int ci = c0 + CI_CH + ci_l;
          if ((unsigned)ih < (unsigned)HIN && (unsigned)iw < (unsigned)WIN) {
            v = (ci < C1) ? in1[((long)(b * C1 + ci) * HIN + ih) * WIN + iw]
                          : in2[((long)(b * C2 + ci - C1) * HIN + ih) * WIN + iw];
          }
        }
        sreg[it] = v;
      }
    }
    __syncthreads();
#pragma unroll
    for (int ci_l = 0; ci_l < CI_CH; ++ci_l) {
      int ci = c0 + ci_l;
      float x[3][3];
#pragma unroll
      for (int r = 0; r < 3; ++r)
#pragma unroll
        for (int c = 0; c < 3; ++c)
          x[r][c] = lin[cur][ci_l * (LR * PW) + (dt + r) * PW + s + c];
#pragma unroll
      for (int co = 0; co < CO_T; ++co) {
        const float* wp = &w_s[(ci * CO_T + co) * 16];
        float4 wa = *(const float4*)(wp);
        float4 wb = *(const float4*)(wp + 4);
        float4 wc = *(const float4*)(wp + 8);
        float4 wd = *(const float4*)(wp + 12);
        aee[co] += wb.y * x[1][1] + wb.w * x[1][0] + wd.y * x[0][1] + wd.w * x[0][0];
        aeo[co] += wb.x * x[1][2] + wb.z * x[1][1] + wd.x * x[0][2] + wd.z * x[0][1];
        aoe[co] += wa.y * x[2][1] + wa.w * x[2][0] + wc.y * x[1][1] + wc.w * x[1][0];
        aoo[co] += wa.x * x[2][2] + wa.z * x[2][1] + wc.x * x[1][2] + wc.z * x[1][1];
      }
    }
    if (has_next) {
#pragma unroll
      for (int it = 0; it < SITER; ++it) {
        int i = tid + it * 256;
        if (i < TOTAL) lin[cur ^ 1][i] = sreg[it];
      }
    }
    cur ^= 1;
  }

#pragma unroll
  for (int co = 0; co < CO_T; ++co) {
    long base = ((long)(b * COUT + co0 + co) * Ho + 2 * t) * Wo + 2 * s;
    float2 r0; r0.x = fmaxf(aee[co], 0.f); r0.y = fmaxf(aeo[co], 0.f);
    float2 r1; r1.x = fmaxf(aoe[co], 0.f); r1.y = fmaxf(aoo[co], 0.f);
    *(float2*)(out + base) = r0;
    *(float2*)(out + base + Wo) = r1;
  }
}

// ============== wsum precompute for style-merge broadcast channels ==========
__global__ __launch_bounds__(256) void k_wsum(
    const float* __restrict__ w, const float* __restrict__ sf,
    float* __restrict__ wsum)
{
  int b = blockIdx.x;
  for (int i = threadIdx.x; i < 576; i += 256) {
    int co = i / 9, t = i % 9;
    float s = 0.f;
    for (int ci = 0; ci < 64; ++ci)
      s += w[((long)co * 128 + 64 + ci) * 9 + t] * sf[b * 64 + ci];
    wsum[((long)b * 64 + co) * 9 + t] = s;
  }
}

// ===== merged q/k/v projection: y<4 -> V quarter, y==4 -> Q+K ==============
__global__ __launch_bounds__(256) void k_qkvproj(
    const float* __restrict__ x,
    const float* __restrict__ wq, const float* __restrict__ bq,
    const float* __restrict__ wk, const float* __restrict__ bk,
    const float* __restrict__ wv, const float* __restrict__ bv,
    float* __restrict__ qT, float* __restrict__ kC,
    float* __restrict__ vT, int N)
{
  int idx = blockIdx.x * 256 + threadIdx.x;
  int n = idx % N, b = idx / N;
  const float* src = x + (long)b * 64 * N + n;
  if (blockIdx.y < 4) {
    int cq = blockIdx.y * 16;
    float va[16];
#pragma unroll
    for (int c = 0; c < 16; ++c) va[c] = bv[cq + c];
    for (int ci = 0; ci < 64; ++ci) {
      float xv = src[(long)ci * N];
#pragma unroll
      for (int c = 0; c < 16; ++c) va[c] += wv[(cq + c) * 64 + ci] * xv;
    }
    float* vo = vT + ((long)b * N + n) * 64 + cq;
#pragma unroll
    for (int c = 0; c < 16; c += 4) {
      float4 o; o.x = va[c]; o.y = va[c+1]; o.z = va[c+2]; o.w = va[c+3];
      *(float4*)(vo + c) = o;
    }
  } else {
    float qa[8], ka[8];
#pragma unroll
    for (int c = 0; c < 8; ++c) { qa[c] = bq[c]; ka[c] = bk[c]; }
    for (int ci = 0; ci < 64; ++ci) {
      float xv = src[(long)ci * N];
#pragma unroll
      for (int c = 0; c < 8; ++c) {
        qa[c] += wq[c * 64 + ci] * xv;
        ka[c] += wk[c * 64 + ci] * xv;
      }
    }
    float* qo = qT + ((long)b * N + n) * 8;
#pragma unroll
    for (int c = 0; c < 8; ++c) qo[c] = qa[c];
#pragma unroll
    for (int c = 0; c < 8; ++c) kC[((long)b * 8 + c) * N + n] = ka[c];
  }
}

// ====== flash attention v6b: p_s stride 133 (write-conflict-free) ==========
// grid (32 n0-tiles, B, 6 splits): splits 0-3 have 11 tiles, 4-5 have 10.
__global__ __launch_bounds__(256) void k_fattn(
    const float* __restrict__ qT, const float* __restrict__ kC,
    const float* __restrict__ vT, float* __restrict__ o_part,
    float* __restrict__ l_part, int N)
{
  __shared__ float k_s[8][68];
  __shared__ float v_s[64 * 64];     // [m][c]
  __shared__ float p_s[64 * 133];    // [m][q] stride 133; reused as o_sT[c][q]
  // stride 133: row step mod 32 banks = 5, so 8 xg-lanes (m = xg*8+j) spread
  // across banks on P-writes instead of aliasing one 4-bank group (stride 132).

  int tid = threadIdx.x;
  int n0 = blockIdx.x * 128;
  int b = blockIdx.y;
  int split = blockIdx.z;
  int qg = tid >> 3;   // 0..31
  int xg = tid & 7;    // 0..7

  int tstart = split * 10 + min(split, 4);
  int tcount = 10 + (split < 4 ? 1 : 0);

  float qv[4][8];
#pragma unroll
  for (int i = 0; i < 4; ++i) {
    const float4* qp = (const float4*)(qT + ((long)b * N + n0 + qg * 4 + i) * 8);
    float4 a = qp[0], c = qp[1];
    qv[i][0]=a.x; qv[i][1]=a.y; qv[i][2]=a.z; qv[i][3]=a.w;
    qv[i][4]=c.x; qv[i][5]=c.y; qv[i][6]=c.z; qv[i][7]=c.w;
  }

  float o[4][8];
#pragma unroll
  for (int i = 0; i < 4; ++i)
#pragma unroll
    for (int j = 0; j < 8; ++j) o[i][j] = 0.f;
  float l[4] = {0.f, 0.f, 0.f, 0.f};

  const float* kbase = kC + (long)b * 8 * N;
  const float* vbase = vT + (long)b * N * 64;

  for (int t = tstart; t < tstart + tcount; ++t) {
    int m0 = t * 64;
    float4 vr0, vr1, vr2, vr3;
    {
      const float4* vp = (const float4*)(vbase + (long)m0 * 64) + tid;
      vr0 = vp[0]; vr1 = vp[256]; vr2 = vp[512]; vr3 = vp[768];
    }
    {
      int kk = tid >> 5, seg = tid & 31;
      float2 kv2 = *(const float2*)(kbase + (long)kk * N + m0 + seg * 2);
      *(float2*)&k_s[kk][seg * 2] = kv2;
    }
    __syncthreads();   // (A) k_s ready; all waves done with prev p_s/v_s

    float s[4][8];
#pragma unroll
    for (int i = 0; i < 4; ++i)
#pragma unroll
      for (int j = 0; j < 8; ++j) s[i][j] = 0.f;
#pragma unroll
    for (int kk = 0; kk < 8; ++kk) {
      float4 ka = *(const float4*)&k_s[kk][xg * 8];
      float4 kb = *(const float4*)&k_s[kk][xg * 8 + 4];
#pragma unroll
      for (int i = 0; i < 4; ++i) {
        float q = qv[i][kk];
        s[i][0] += q * ka.x; s[i][1] += q * ka.y; s[i][2] += q * ka.z; s[i][3] += q * ka.w;
        s[i][4] += q * kb.x; s[i][5] += q * kb.y; s[i][6] += q * kb.z; s[i][7] += q * kb.w;
      }
    }
#pragma unroll
    for (int i = 0; i < 4; ++i) {
#pragma unroll
      for (int j = 0; j < 8; ++j) {
        s[i][j] = __expf(s[i][j]);
        l[i] += s[i][j];
      }
    }
#pragma unroll
    for (int j = 0; j < 8; ++j) {
      float4 w4; w4.x = s[0][j]; w4.y = s[1][j]; w4.z = s[2][j]; w4.w = s[3][j];
      *(float4*)&p_s[(xg * 8 + j) * 133 + qg * 4] = w4;
    }
    {
      float* vd = v_s + tid * 4;
      *(float4*)(vd +    0) = vr0;
      *(float4*)(vd + 1024) = vr1;
      *(float4*)(vd + 2048) = vr2;
      *(float4*)(vd + 3072) = vr3;
    }
    __syncthreads();   // (B) p_s + v_s ready

#pragma unroll 4
    for (int mm = 0; mm < 16; ++mm) {
#pragma unroll
      for (int j = 0; j < 4; ++j) {
        int m = mm * 4 + j;
        float4 pr = *(const float4*)&p_s[m * 133 + qg * 4];
        float4 va = *(const float4*)&v_s[m * 64 + xg * 8];
        float4 vb4 = *(const float4*)&v_s[m * 64 + xg * 8 + 4];
#pragma unroll
        for (int i = 0; i < 4; ++i) {
          float p = (i == 0) ? pr.x : (i == 1) ? pr.y : (i == 2) ? pr.z : pr.w;
          o[i][0] += p * va.x;  o[i][1] += p * va.y;
          o[i][2] += p * va.z;  o[i][3] += p * va.w;
          o[i][4] += p * vb4.x; o[i][5] += p * vb4.y;
          o[i][6] += p * vb4.z; o[i][7] += p * vb4.w;
        }
      }
    }
    // no 3rd barrier: next tile's barrier (A) orders p_s/v_s overwrites
  }

#pragma unroll
  for (int i = 0; i < 4; ++i) {
#pragma unroll
    for (int d = 1; d < 8; d <<= 1) l[i] += __shfl_xor(l[i], d);
  }

  __syncthreads();   // all waves done with final PV before p_s reuse
#pragma unroll
  for (int j = 0; j < 8; ++j) {
    float4 w4; w4.x = o[0][j]; w4.y = o[1][j]; w4.z = o[2][j]; w4.w = o[3][j];
    *(float4*)&p_s[(xg * 8 + j) * 133 + qg * 4] = w4;
  }
  __syncthreads();
  float* obase = o_part + (long)split * 1048576 + ((long)b * 64) * 4096 + n0;
  for (int idx = tid; idx < 2048; idx += 256) {
    int c = idx >> 5, q4 = (idx & 31) << 2;
    float4 v4 = *(const float4*)&p_s[c * 133 + q4];
    *(float4*)(obase + (long)c * 4096 + q4) = v4;
  }
  if (xg == 0) {
    float4 lw; lw.x = l[0]; lw.y = l[1]; lw.z = l[2]; lw.w = l[3];
    *(float4*)&l_part[((long)split * 4 + b) * 4096 + n0 + qg * 4] = lw;
  }
}

// ============== attention combine (6 partials): out = g*(Σo)/(Σl) + x =======
__global__ __launch_bounds__(256) void k_attnfin(
    const float* __restrict__ op, const float* __restrict__ lp,
    const float* __restrict__ xb, const float* __restrict__ gamma_p,
    float* __restrict__ outb)
{
  int idx = blockIdx.x * 256 + threadIdx.x;   // covers 4*64*4096 = 1048576
  int n = idx & 4095;
  int b = idx >> 18;
  float g = gamma_p[0];
  float o = op[idx] + op[idx + 1048576] + op[idx + 2097152]
          + op[idx + 3145728] + op[idx + 4194304] + op[idx + 5242880];
  const float* lb = lp + b * 4096 + n;
  float l = lb[0] + lb[16384] + lb[32768] + lb[49152] + lb[65536] + lb[81920];
  outb[idx] = g * o / l + xb[idx];
}

// ================= adaptive avg pool to 8x8 ================================
__global__ __launch_bounds__(256) void k_pool8(
    const float* __restrict__ in, float* __restrict__ out, int B, int C, int H, int W)
{
  int idx = blockIdx.x * 256 + threadIdx.x;
  int total = B * C * 64;
  if (idx >= total) return;
  int ow = idx & 7, oh = (idx >> 3) & 7;
  int c = (idx >> 6) % C, b = idx / (64 * C);
  int bh = H / 8, bw = W / 8;
  const float* src = in + ((long)(b * C + c)) * H * W;
  float s = 0.f;
  for (int y = 0; y < bh; ++y)
    for (int x = 0; x < bw; ++x)
      s += src[(oh * bh + y) * W + ow * bw + x];
  out[idx] = s / (float)(bh * bw);
}

// ================= fc + relu (wave per output) ==============================
__global__ __launch_bounds__(256) void k_fc_relu(
    const float* __restrict__ in, const float* __restrict__ w,
    const float* __restrict__ bias, float* __restrict__ out, int B, int K, int O)
{
  int gi = blockIdx.x * 4 + (threadIdx.x >> 6);
  int lane = threadIdx.x & 63;
  if (gi >= B * O) return;
  int b = gi / O, o = gi % O;
  const float* x = in + (long)b * K;
  const float* wp = w + (long)o * K;
  float s = 0.f;
  for (int i = lane; i < K; i += 64) s += x[i] * wp[i];
#pragma unroll
  for (int d = 1; d < 64; d <<= 1) s += __shfl_xor(s, d);
  if (lane == 0) out[gi] = fmaxf(s + bias[o], 0.f);
}

// ====== fused line filter: row stats (incl. halo) + 5-tap apply =============
// block = (row-tile, plane). stats for TR+4 clamped rows -> LDS, then apply.
template<int W, int H, int TR>
__global__ __launch_bounds__(256) void k_lf_fused(
    const float* __restrict__ x, float* __restrict__ out,
    float strength, int do_tanh)
{
  __shared__ float stat[TR + 4];
  int tid = threadIdx.x;
  int lane = tid & 63, wid = tid >> 6;
  int r0 = blockIdx.x * TR;
  int bc = blockIdx.y;
  const float* plane = x + (long)bc * H * W;

  // stats for rows r0-2 .. r0+TR+1 (clamped)
  for (int r = wid; r < TR + 4; r += 4) {
    int row = r0 - 2 + r;
    row = row < 0 ? 0 : (row >= H ? H - 1 : row);
    const float* p = plane + (long)row * W;
    float s = 0.f;
    for (int i = lane; i < W; i += 64) s += p[i];
#pragma unroll
    for (int d = 1; d < 64; d <<= 1) s += __shfl_xor(s, d);
    float mean = s / (float)W;
    float v = 0.f;
    for (int i = lane; i < W; i += 64) { float t = p[i] - mean; v += t * t; }
#pragma unroll
    for (int d = 1; d < 64; d <<= 1) v += __shfl_xor(v, d);
    float stdv = sqrtf(v / (float)(W - 1));
    float mask = 1.f / (1.f + __expf(-(0.05f - stdv) * 10.f));
    if (lane == 0) stat[r] = mask;
  }
  __syncthreads();

  // apply: TR rows x W cols, float4 per thread-iter
  constexpr int WQ = W / 4;
  for (int idx = tid; idx < TR * WQ; idx += 256) {
    int w4 = idx % WQ;
    int hr = idx / WQ;
    int h = r0 + hr;
    const float* px = plane + w4 * 4;
    float4 vs; vs.x = 0.f; vs.y = 0.f; vs.z = 0.f; vs.w = 0.f;
    float mb = 0.f;
#pragma unroll
    for (int d = -2; d <= 2; ++d) {
      int hh = h + d; hh = hh < 0 ? 0 : (hh >= H ? H - 1 : hh);
      float4 t = *(const float4*)(px + (long)hh * W);
      vs.x += t.x; vs.y += t.y; vs.z += t.z; vs.w += t.w;
      mb += stat[hr + d + 2];
    }
    float m = mb * 0.2f * strength;
    float om = 1.f - m;
    float ms = m * 0.2f;
    float4 xv = *(const float4*)(px + (long)h * W);
    float4 r;
    r.x = xv.x * om + vs.x * ms;
    r.y = xv.y * om + vs.y * ms;
    r.z = xv.z * om + vs.z * ms;
    r.w = xv.w * om + vs.w * ms;
    if (do_tanh) {
      r.x = tanhf(r.x); r.y = tanhf(r.y); r.z = tanhf(r.z); r.w = tanhf(r.w);
    }
    *(float4*)(out + (long)bc * H * W + (long)h * W + w4 * 4) = r;
  }
}

// ---------------- launch ----------------
static inline unsigned gdiv(long total) { return (unsigned)((total + 255) / 256); }

extern "C" void kernel_launch(void* const* d_in, const int* in_sizes, int n_in,
                              void* d_out, int out_size, void* d_ws, size_t ws_size,
                              hipStream_t stream)
{
  (void)in_sizes; (void)n_in; (void)out_size; (void)ws_size;
  const float* sketch   = (const float*)d_in[0];
  const float* depth    = (const float*)d_in[1];
  const float* style    = (const float*)d_in[2];
  const float* enc1_w   = (const float*)d_in[3];
  const float* enc1_b   = (const float*)d_in[4];
  const float* enc2_w   = (const float*)d_in[5];
  const float* enc2_b   = (const float*)d_in[6];
  const float* enc3_w   = (const float*)d_in[7];
  const float* enc3_b   = (const float*)d_in[8];
  const float* se1_w    = (const float*)d_in[9];
  const float* se1_b    = (const float*)d_in[10];
  const float* se2_w    = (const float*)d_in[11];
  const float* se2_b    = (const float*)d_in[12];
  const float* se3_w    = (const float*)d_in[13];
  const float* se3_b    = (const float*)d_in[14];
  const float* sp1_w    = (const float*)d_in[15];
  const float* sp1_b    = (const float*)d_in[16];
  const float* sp2_w    = (const float*)d_in[17];
  const float* sp2_b    = (const float*)d_in[18];
  const float* sm_w     = (const float*)d_in[19];
  const float* sm_b     = (const float*)d_in[20];
  const float* attn_q_w = (const float*)d_in[21];
  const float* attn_q_b = (const float*)d_in[22];
  const float* attn_k_w = (const float*)d_in[23];
  const float* attn_k_b = (const float*)d_in[24];
  const float* attn_v_w = (const float*)d_in[25];
  const float* attn_v_b = (const float*)d_in[26];
  const float* attn_g   = (const float*)d_in[27];
  const float* bn_w     = (const float*)d_in[28];
  const float* bn_b     = (const float*)d_in[29];
  const float* dec3_w   = (const float*)d_in[30];
  const float* dec3_b   = (const float*)d_in[31];
  const float* dec2_w   = (const float*)d_in[32];
  const float* dec2_b   = (const float*)d_in[33];
  const float* dec1_w   = (const float*)d_in[34];
  const float* dec1_b   = (const float*)d_in[35];
  float* out = (float*)d_out;

  float* ws    = (float*)d_ws;
  float* e1    = ws + OFF_E1;
  float* e2    = ws + OFF_E2;
  float* e3a   = ws + OFF_E3A;
  float* e3b   = ws + OFF_E3B;
  float* big16 = ws + OFF_BIG16;   // also attn o_part (6 x 1M, spans into big8)
  float* big8  = ws + OFF_BIG8;
  float* b4    = ws + OFF_B4;
  float* vbuf  = ws + OFF_V;
  float* qbuf  = ws + OFF_Q;
  float* kbuf  = ws + OFF_K;
  float* pool  = ws + OFF_POOL;
  float* sf1   = ws + OFF_SF1;
  float* sf2   = ws + OFF_SF2;
  float* d2lf  = ws + OFF_D2LF;    // head doubles as attn l_part
  float* pre   = ws + OFF_PRE;

  const int B = 4;

  // ---- stage 1: enc1 and se1 (independent) ----
  k_c3<1,1,0, 2, 256,256,1, 2, 16,16, 1,0,0><<<dim3(256, B, 1), 256, 0, stream>>>(
      sketch, depth, enc1_w, enc1_b, nullptr, e1);
  k_c3<3,0,0, 3, 256,256,1, 3, 16,16, 1,0,0><<<dim3(256, B, 1), 256, 0, stream>>>(
      style, nullptr, se1_w, se1_b, nullptr, big16);

  // ---- stage 2: enc2 + se2 merged; enc3 + se3 merged ----
  k_c4dual<16,2,32,8, 256,256, 128,2><<<dim3(64, B, 8), 256, 0, stream>>>(
      e1, enc2_w, enc2_b, e2, big16, se2_w, se2_b, big8);
  k_c4dual<32,2,64,4, 128,128, 64,4><<<dim3(16, B, 32), 256, 0, stream>>>(
      e2, enc3_w, enc3_b, e3a, big8, se3_w, se3_b, b4);

  // ---- line_filter(e3, 0.8): e3a -> e3b (fused stats+apply) ----
  k_lf_fused<64,64,16><<<dim3(4, B*64), 256, 0, stream>>>(e3a, e3b, 0.8f, 0);

  // ---- style head ----
  k_pool8<<<gdiv(B*64*64), 256, 0, stream>>>(b4, pool, B, 64, 64, 64);
  k_fc_relu<<<(B*64 + 3)/4, 256, 0, stream>>>(pool, sp1_w, sp1_b, sf1, B, 4096, 64);
  k_fc_relu<<<(B*64 + 3)/4, 256, 0, stream>>>(sf1, sp2_w, sp2_b, sf2, B, 64, 64);

  // ---- style merge (+mix fused, bcast channels via wsum) ----
  k_wsum<<<B, 256, 0, stream>>>(sm_w, sf2, pool);
  k_c3<64,0,0, 128, 64,64,4, 8, 64,4, 1,1,1><<<dim3(16, B, 16), 256, 0, stream>>>(
      e3b, nullptr, sm_w, sm_b, pool, e3a);

  // ---- self-attention on e3a -> e3b (merged proj, uneven KV-split x6) ----
  k_qkvproj<<<dim3(64, 5), 256, 0, stream>>>(
      e3a, attn_q_w, attn_q_b, attn_k_w, attn_k_b, attn_v_w, attn_v_b,
      qbuf, kbuf, vbuf, 4096);
  k_fattn<<<dim3(32, B, 6), 256, 0, stream>>>(qbuf, kbuf, vbuf, big16, d2lf, 4096);
  k_attnfin<<<4096, 256, 0, stream>>>(big16, d2lf, e3a, attn_g, e3b);

  // ---- bottleneck + decoder ----
  k_c3<64,0,0, 64, 64,64,4, 8, 64,4, 1,0,0><<<dim3(16, B, 16), 256, 0, stream>>>(
      e3b, nullptr, bn_w, bn_b, nullptr, b4);
  k_ct<64,64,32,2, 64,64, 4,4><<<dim3(16, B, 16), 256, 0, stream>>>(b4, e3b, dec3_w, dec3_b, big8);
  k_ct<32,32,16,4, 128,128, 2,4><<<dim3(64, B, 4), 256, 0, stream>>>(big8, e2, dec2_w, dec2_b, big16);
  // line_filter(d2, 0.8): big16 -> d2lf (fused)
  k_lf_fused<256,256,16><<<dim3(16, B*16), 256, 0, stream>>>(big16, d2lf, 0.8f, 0);
  k_c3<16,16,0, 32, 256,256,1, 8, 3,3, 0,0,0><<<dim3(256, B, 1), 256, 0, stream>>>(
      d2lf, e1, dec1_w, dec1_b, nullptr, pre);
  // final: tanh(line_filter(pre, 0.9)) -> out (fused)
  k_lf_fused<256,256,8><<<dim3(32, B*3), 256, 0, stream>>>(pre, out, 0.9f, 1);
}